// Round 1
// baseline (8716.882 us; speedup 1.0000x reference)
//
#include <hip/hip_runtime.h>

#define NN 100000
#define NE 1600000
#define DD 128
#define NG 256
#define XX 16
#define NL 3
#define LNEPS 1e-5f

// x0 = (1+eps[l]) * h   (elementwise, float4)
__global__ __launch_bounds__(256) void scale_init_k(const float* __restrict__ h,
                                                    float* __restrict__ x0,
                                                    const float* __restrict__ eps, int l) {
    float e = 1.0f + eps[l];
    size_t i = (size_t)blockIdx.x * blockDim.x + threadIdx.x;
    size_t tot = (size_t)NN * DD / 4;
    const float4* hv = (const float4*)h;
    float4* xv = (float4*)x0;
    for (; i < tot; i += (size_t)gridDim.x * blockDim.x) {
        float4 v = hv[i];
        v.x *= e; v.y *= e; v.z *= e; v.w *= e;
        xv[i] = v;
    }
}

// x0[dst[e]] += h[src[e]]  (HW f32 atomics, 4 floats per thread)
__global__ __launch_bounds__(256) void edge_k(const float* __restrict__ h,
                                              const int* __restrict__ src,
                                              const int* __restrict__ dst,
                                              float* __restrict__ x0) {
    size_t idx = (size_t)blockIdx.x * 256 + threadIdx.x;
    if (idx >= (size_t)NE * 32) return;
    int e = (int)(idx >> 5), q = (int)(idx & 31);
    int s = src[e], d = dst[e];
    const float4 v = *(const float4*)&h[(size_t)s * DD + q * 4];
    float* p = &x0[(size_t)d * DD + q * 4];
    unsafeAtomicAdd(p + 0, v.x);
    unsafeAtomicAdd(p + 1, v.y);
    unsafeAtomicAdd(p + 2, v.z);
    unsafeAtomicAdd(p + 3, v.w);
}

// y = relu(LN(x @ W + bias; gamma, beta))   [nrows x 128] @ [128 x 128]
// block: 256 threads = 32 col-groups (4 cols) x 8 row-groups (8 rows); 64 rows/block
__global__ __launch_bounds__(256) void gemm_ln_relu_k(const float* __restrict__ x,
                                                      const float* __restrict__ W,
                                                      const float* __restrict__ bias,
                                                      const float* __restrict__ gamma,
                                                      const float* __restrict__ beta,
                                                      float* __restrict__ y, int nrows) {
    __shared__ float xt[64][132];   // x tile, pad 4 floats: 16B-aligned rows, conflict-free
    __shared__ float ws[32][128];   // W quarter (k-slice)
    const int tid = threadIdx.x;
    const int cg = tid & 31;        // col group: cols cg*4 .. cg*4+3
    const int rg = tid >> 5;        // row group: rows rg*8 .. rg*8+7
    const int rb = blockIdx.x * 64;

    // stage x tile (coalesced float4 reads, conflict-free LDS writes)
    #pragma unroll
    for (int i = 0; i < 8; ++i) {
        int f = tid + i * 256;
        int kq = f & 31, row = f >> 5;
        int gr = rb + row;
        int sr = gr < nrows ? gr : 0;
        float4 v = *(const float4*)&x[(size_t)sr * DD + kq * 4];
        *(float4*)&xt[row][kq * 4] = v;
    }

    float acc[8][4];
    #pragma unroll
    for (int j = 0; j < 8; ++j) { acc[j][0] = acc[j][1] = acc[j][2] = acc[j][3] = 0.f; }

    for (int kh = 0; kh < 4; ++kh) {
        __syncthreads();
        // stage W rows kh*32 .. kh*32+31
        #pragma unroll
        for (int i = 0; i < 4; ++i) {
            int f = tid + i * 256;
            int c4 = f & 31, kr = f >> 5;
            *(float4*)&ws[kr][c4 * 4] =
                *(const float4*)&W[(size_t)(kh * 32 + kr) * DD + c4 * 4];
        }
        __syncthreads();
        #pragma unroll 4
        for (int k2 = 0; k2 < 32; k2 += 2) {
            float4 w0 = *(const float4*)&ws[k2][cg * 4];
            float4 w1 = *(const float4*)&ws[k2 + 1][cg * 4];
            #pragma unroll
            for (int j = 0; j < 8; ++j) {
                float2 xv = *(const float2*)&xt[rg * 8 + j][kh * 32 + k2];
                acc[j][0] += xv.x * w0.x; acc[j][1] += xv.x * w0.y;
                acc[j][2] += xv.x * w0.z; acc[j][3] += xv.x * w0.w;
                acc[j][0] += xv.y * w1.x; acc[j][1] += xv.y * w1.y;
                acc[j][2] += xv.y * w1.z; acc[j][3] += xv.y * w1.w;
            }
        }
    }

    float4 bv  = *(const float4*)&bias[cg * 4];
    float4 gv  = *(const float4*)&gamma[cg * 4];
    float4 bev = *(const float4*)&beta[cg * 4];
    #pragma unroll
    for (int j = 0; j < 8; ++j) {
        float v0 = acc[j][0] + bv.x, v1 = acc[j][1] + bv.y;
        float v2 = acc[j][2] + bv.z, v3 = acc[j][3] + bv.w;
        float s1 = v0 + v1 + v2 + v3;
        float s2 = v0 * v0 + v1 * v1 + v2 * v2 + v3 * v3;
        #pragma unroll
        for (int m = 1; m <= 16; m <<= 1) {   // reduce across 32 col-groups (lane bits 0-4)
            s1 += __shfl_xor(s1, m);
            s2 += __shfl_xor(s2, m);
        }
        float mean = s1 * (1.0f / DD);
        float var  = s2 * (1.0f / DD) - mean * mean;
        float inv  = rsqrtf(var + LNEPS);
        float4 o;
        o.x = fmaxf((v0 - mean) * inv * gv.x + bev.x, 0.f);
        o.y = fmaxf((v1 - mean) * inv * gv.y + bev.y, 0.f);
        o.z = fmaxf((v2 - mean) * inv * gv.z + bev.z, 0.f);
        o.w = fmaxf((v3 - mean) * inv * gv.w + bev.w, 0.f);
        int gr = rb + rg * 8 + j;
        if (gr < nrows) *(float4*)&y[(size_t)gr * DD + cg * 4] = o;
    }
}

__device__ __forceinline__ int lower_bound_i(const int* a, int n, int v) {
    int lo = 0, hi = n;
    while (lo < hi) { int m = (lo + hi) >> 1; if (a[m] < v) lo = m + 1; else hi = m; }
    return lo;
}

// per-graph: segment-sum pool (gid sorted) + concat desc + fc1 + LN + relu + fc2
__global__ __launch_bounds__(128) void head_k(const float* __restrict__ h,
                                              const int* __restrict__ gid,
                                              const float* __restrict__ desc,
                                              const float* __restrict__ fc1W,
                                              const float* __restrict__ fc1b,
                                              const float* __restrict__ n1g,
                                              const float* __restrict__ n1b,
                                              const float* __restrict__ fc2W,
                                              const float* __restrict__ fc2b,
                                              float* __restrict__ out) {
    const int g = blockIdx.x;
    const int c = threadIdx.x;
    __shared__ float cat[DD + XX];
    __shared__ float red[4];
    int lo = lower_bound_i(gid, NN, g);
    int hi = lower_bound_i(gid, NN, g + 1);
    float s = 0.f;
    for (int i = lo; i < hi; ++i) s += h[(size_t)i * DD + c];
    cat[c] = s;
    if (c < XX) cat[DD + c] = desc[g * XX + c];
    __syncthreads();
    float z = fc1b[c];
    for (int k = 0; k < DD + XX; ++k) z += cat[k] * fc1W[k * DD + c];
    float s1 = z, s2 = z * z;
    #pragma unroll
    for (int m = 1; m <= 32; m <<= 1) { s1 += __shfl_xor(s1, m); s2 += __shfl_xor(s2, m); }
    int wid = c >> 6, lane = c & 63;
    if (lane == 0) { red[wid] = s1; red[2 + wid] = s2; }
    __syncthreads();
    s1 = red[0] + red[1]; s2 = red[2] + red[3];
    float mean = s1 * (1.0f / DD);
    float var  = s2 * (1.0f / DD) - mean * mean;
    float inv  = rsqrtf(var + LNEPS);
    float zr = fmaxf((z - mean) * inv * n1g[c] + n1b[c], 0.f);
    float p = zr * fc2W[c];
    #pragma unroll
    for (int m = 1; m <= 32; m <<= 1) p += __shfl_xor(p, m);
    __syncthreads();
    if (lane == 0) red[wid] = p;
    __syncthreads();
    if (c == 0) out[g] = red[0] + red[1] + fc2b[0];
}

extern "C" void kernel_launch(void* const* d_in, const int* in_sizes, int n_in,
                              void* d_out, int out_size, void* d_ws, size_t ws_size,
                              hipStream_t stream) {
    const float* h    = (const float*)d_in[0];
    const float* desc = (const float*)d_in[1];
    const int*   src  = (const int*)d_in[2];
    const int*   dst  = (const int*)d_in[3];
    const int*   gid  = (const int*)d_in[4];
    const float* W1   = (const float*)d_in[5];
    const float* b1   = (const float*)d_in[6];
    const float* g1   = (const float*)d_in[7];
    const float* be1  = (const float*)d_in[8];
    const float* W2   = (const float*)d_in[9];
    const float* b2   = (const float*)d_in[10];
    const float* eps  = (const float*)d_in[11];
    const float* ng   = (const float*)d_in[12];
    const float* nb   = (const float*)d_in[13];
    const float* fc1W = (const float*)d_in[14];
    const float* fc1b = (const float*)d_in[15];
    const float* n1g  = (const float*)d_in[16];
    const float* n1b  = (const float*)d_in[17];
    const float* fc2W = (const float*)d_in[18];
    const float* fc2b = (const float*)d_in[19];
    float* out = (float*)d_out;

    float* bufA = (float*)d_ws;
    float* bufB = bufA + (size_t)NN * DD;

    const float* cur = h;
    for (int l = 0; l < NL; ++l) {
        float* x0 = (l & 1) ? bufB : bufA;   // agg buffer
        float* x1 = (l & 1) ? bufA : bufB;   // MLP mid
        float* nx = x0;                      // next h (overwrites x0, safe)
        scale_init_k<<<12500, 256, 0, stream>>>(cur, x0, eps, l);
        edge_k<<<(int)(((size_t)NE * 32 + 255) / 256), 256, 0, stream>>>(cur, src, dst, x0);
        gemm_ln_relu_k<<<(NN + 63) / 64, 256, 0, stream>>>(
            x0, W1 + (size_t)l * DD * DD, b1 + l * DD, g1 + l * DD, be1 + l * DD, x1, NN);
        gemm_ln_relu_k<<<(NN + 63) / 64, 256, 0, stream>>>(
            x1, W2 + (size_t)l * DD * DD, b2 + l * DD, ng + l * DD, nb + l * DD, nx, NN);
        cur = nx;
    }
    head_k<<<NG, 128, 0, stream>>>(cur, gid, desc, fc1W, fc1b, n1g, n1b, fc2W, fc2b, out);
}

// Round 2
// 1190.954 us; speedup vs baseline: 7.3192x; 7.3192x over previous
//
#include <hip/hip_runtime.h>

#define NN 100000
#define NE 1600000
#define DD 128
#define NG 256
#define XX 16
#define NL 3
#define LNEPS 1e-5f

// ---------------- CSR build (once per call; ws is re-poisoned every call) ----------------

__global__ __launch_bounds__(256) void zero_int_k(int* __restrict__ p, int n) {
    int i = blockIdx.x * 256 + threadIdx.x;
    if (i < n) p[i] = 0;
}

__global__ __launch_bounds__(256) void count_k(const int* __restrict__ dst,
                                               int* __restrict__ cnt) {
    int e = blockIdx.x * 256 + threadIdx.x;
    if (e < NE) atomicAdd(&cnt[dst[e]], 1);
}

// per-block sum of 256 counts -> bsum[b]
__global__ __launch_bounds__(256) void block_reduce_k(const int* __restrict__ cnt,
                                                      int* __restrict__ bsum) {
    __shared__ int sw[4];
    int i = blockIdx.x * 256 + threadIdx.x;
    int v = i < NN ? cnt[i] : 0;
    #pragma unroll
    for (int m = 1; m <= 32; m <<= 1) v += __shfl_xor(v, m);
    int lane = threadIdx.x & 63, wid = threadIdx.x >> 6;
    if (lane == 0) sw[wid] = v;
    __syncthreads();
    if (threadIdx.x == 0) bsum[blockIdx.x] = sw[0] + sw[1] + sw[2] + sw[3];
}

// sequential exclusive scan of block sums (nb ~ 391, once per call -> trivial)
__global__ void scan_bsums_k(int* __restrict__ bsum, int nb, int* __restrict__ row_ptr) {
    if (threadIdx.x == 0 && blockIdx.x == 0) {
        int run = 0;
        for (int i = 0; i < nb; ++i) { int v = bsum[i]; bsum[i] = run; run += v; }
        row_ptr[NN] = NE;
    }
}

// in-block exclusive scan + block offset -> row_ptr
__global__ __launch_bounds__(256) void block_scan_k(const int* __restrict__ cnt,
                                                    const int* __restrict__ bsum,
                                                    int* __restrict__ row_ptr) {
    __shared__ int sd[256];
    int t = threadIdx.x;
    int i = blockIdx.x * 256 + t;
    int v = i < NN ? cnt[i] : 0;
    sd[t] = v;
    __syncthreads();
    #pragma unroll
    for (int off = 1; off < 256; off <<= 1) {
        int x = t >= off ? sd[t - off] : 0;
        __syncthreads();
        sd[t] += x;
        __syncthreads();
    }
    if (i < NN) row_ptr[i] = bsum[blockIdx.x] + sd[t] - v;   // exclusive
}

__global__ __launch_bounds__(256) void fill_k(const int* __restrict__ src,
                                              const int* __restrict__ dst,
                                              const int* __restrict__ row_ptr,
                                              int* __restrict__ cnt,
                                              int* __restrict__ col) {
    int e = blockIdx.x * 256 + threadIdx.x;
    if (e >= NE) return;
    int d = dst[e];
    int slot = row_ptr[d] + atomicAdd(&cnt[d], 1);
    col[slot] = src[e];
}

// ---------------- pull-mode aggregation: x0[v] = (1+eps)*h[v] + sum_{u->v} h[u] ----------------
// 256 threads = 8 nodes x 32 lanes (each lane owns 4 contiguous floats)
__global__ __launch_bounds__(256) void agg_k(const float* __restrict__ h,
                                             const int* __restrict__ row_ptr,
                                             const int* __restrict__ col,
                                             float* __restrict__ x0,
                                             const float* __restrict__ eps, int l) {
    const float e = 1.0f + eps[l];
    const int v = blockIdx.x * 8 + (threadIdx.x >> 5);
    const int q = threadIdx.x & 31;
    if (v >= NN) return;
    const int lo = row_ptr[v], hi = row_ptr[v + 1];
    float4 acc = *(const float4*)&h[(size_t)v * DD + q * 4];
    acc.x *= e; acc.y *= e; acc.z *= e; acc.w *= e;
    for (int i = lo; i < hi; ++i) {
        int s = col[i];
        float4 hv = *(const float4*)&h[(size_t)s * DD + q * 4];
        acc.x += hv.x; acc.y += hv.y; acc.z += hv.z; acc.w += hv.w;
    }
    *(float4*)&x0[(size_t)v * DD + q * 4] = acc;
}

// ---------------- y = relu(LN(x @ W + bias)) ----------------
__global__ __launch_bounds__(256) void gemm_ln_relu_k(const float* __restrict__ x,
                                                      const float* __restrict__ W,
                                                      const float* __restrict__ bias,
                                                      const float* __restrict__ gamma,
                                                      const float* __restrict__ beta,
                                                      float* __restrict__ y, int nrows) {
    __shared__ float xt[64][132];
    __shared__ float ws[32][128];
    const int tid = threadIdx.x;
    const int cg = tid & 31;
    const int rg = tid >> 5;
    const int rb = blockIdx.x * 64;

    #pragma unroll
    for (int i = 0; i < 8; ++i) {
        int f = tid + i * 256;
        int kq = f & 31, row = f >> 5;
        int gr = rb + row;
        int sr = gr < nrows ? gr : 0;
        float4 v = *(const float4*)&x[(size_t)sr * DD + kq * 4];
        *(float4*)&xt[row][kq * 4] = v;
    }

    float acc[8][4];
    #pragma unroll
    for (int j = 0; j < 8; ++j) { acc[j][0] = acc[j][1] = acc[j][2] = acc[j][3] = 0.f; }

    for (int kh = 0; kh < 4; ++kh) {
        __syncthreads();
        #pragma unroll
        for (int i = 0; i < 4; ++i) {
            int f = tid + i * 256;
            int c4 = f & 31, kr = f >> 5;
            *(float4*)&ws[kr][c4 * 4] =
                *(const float4*)&W[(size_t)(kh * 32 + kr) * DD + c4 * 4];
        }
        __syncthreads();
        #pragma unroll 4
        for (int k2 = 0; k2 < 32; k2 += 2) {
            float4 w0 = *(const float4*)&ws[k2][cg * 4];
            float4 w1 = *(const float4*)&ws[k2 + 1][cg * 4];
            #pragma unroll
            for (int j = 0; j < 8; ++j) {
                float2 xv = *(const float2*)&xt[rg * 8 + j][kh * 32 + k2];
                acc[j][0] += xv.x * w0.x; acc[j][1] += xv.x * w0.y;
                acc[j][2] += xv.x * w0.z; acc[j][3] += xv.x * w0.w;
                acc[j][0] += xv.y * w1.x; acc[j][1] += xv.y * w1.y;
                acc[j][2] += xv.y * w1.z; acc[j][3] += xv.y * w1.w;
            }
        }
    }

    float4 bv  = *(const float4*)&bias[cg * 4];
    float4 gv  = *(const float4*)&gamma[cg * 4];
    float4 bev = *(const float4*)&beta[cg * 4];
    #pragma unroll
    for (int j = 0; j < 8; ++j) {
        float v0 = acc[j][0] + bv.x, v1 = acc[j][1] + bv.y;
        float v2 = acc[j][2] + bv.z, v3 = acc[j][3] + bv.w;
        float s1 = v0 + v1 + v2 + v3;
        float s2 = v0 * v0 + v1 * v1 + v2 * v2 + v3 * v3;
        #pragma unroll
        for (int m = 1; m <= 16; m <<= 1) {
            s1 += __shfl_xor(s1, m);
            s2 += __shfl_xor(s2, m);
        }
        float mean = s1 * (1.0f / DD);
        float var  = s2 * (1.0f / DD) - mean * mean;
        float inv  = rsqrtf(var + LNEPS);
        float4 o;
        o.x = fmaxf((v0 - mean) * inv * gv.x + bev.x, 0.f);
        o.y = fmaxf((v1 - mean) * inv * gv.y + bev.y, 0.f);
        o.z = fmaxf((v2 - mean) * inv * gv.z + bev.z, 0.f);
        o.w = fmaxf((v3 - mean) * inv * gv.w + bev.w, 0.f);
        int gr = rb + rg * 8 + j;
        if (gr < nrows) *(float4*)&y[(size_t)gr * DD + cg * 4] = o;
    }
}

__device__ __forceinline__ int lower_bound_i(const int* a, int n, int v) {
    int lo = 0, hi = n;
    while (lo < hi) { int m = (lo + hi) >> 1; if (a[m] < v) lo = m + 1; else hi = m; }
    return lo;
}

__global__ __launch_bounds__(128) void head_k(const float* __restrict__ h,
                                              const int* __restrict__ gid,
                                              const float* __restrict__ desc,
                                              const float* __restrict__ fc1W,
                                              const float* __restrict__ fc1b,
                                              const float* __restrict__ n1g,
                                              const float* __restrict__ n1b,
                                              const float* __restrict__ fc2W,
                                              const float* __restrict__ fc2b,
                                              float* __restrict__ out) {
    const int g = blockIdx.x;
    const int c = threadIdx.x;
    __shared__ float cat[DD + XX];
    __shared__ float red[4];
    int lo = lower_bound_i(gid, NN, g);
    int hi = lower_bound_i(gid, NN, g + 1);
    float s = 0.f;
    for (int i = lo; i < hi; ++i) s += h[(size_t)i * DD + c];
    cat[c] = s;
    if (c < XX) cat[DD + c] = desc[g * XX + c];
    __syncthreads();
    float z = fc1b[c];
    for (int k = 0; k < DD + XX; ++k) z += cat[k] * fc1W[k * DD + c];
    float s1 = z, s2 = z * z;
    #pragma unroll
    for (int m = 1; m <= 32; m <<= 1) { s1 += __shfl_xor(s1, m); s2 += __shfl_xor(s2, m); }
    int wid = c >> 6, lane = c & 63;
    if (lane == 0) { red[wid] = s1; red[2 + wid] = s2; }
    __syncthreads();
    s1 = red[0] + red[1]; s2 = red[2] + red[3];
    float mean = s1 * (1.0f / DD);
    float var  = s2 * (1.0f / DD) - mean * mean;
    float inv  = rsqrtf(var + LNEPS);
    float zr = fmaxf((z - mean) * inv * n1g[c] + n1b[c], 0.f);
    float p = zr * fc2W[c];
    #pragma unroll
    for (int m = 1; m <= 32; m <<= 1) p += __shfl_xor(p, m);
    __syncthreads();
    if (lane == 0) red[wid] = p;
    __syncthreads();
    if (c == 0) out[g] = red[0] + red[1] + fc2b[0];
}

extern "C" void kernel_launch(void* const* d_in, const int* in_sizes, int n_in,
                              void* d_out, int out_size, void* d_ws, size_t ws_size,
                              hipStream_t stream) {
    const float* h    = (const float*)d_in[0];
    const float* desc = (const float*)d_in[1];
    const int*   src  = (const int*)d_in[2];
    const int*   dst  = (const int*)d_in[3];
    const int*   gid  = (const int*)d_in[4];
    const float* W1   = (const float*)d_in[5];
    const float* b1   = (const float*)d_in[6];
    const float* g1   = (const float*)d_in[7];
    const float* be1  = (const float*)d_in[8];
    const float* W2   = (const float*)d_in[9];
    const float* b2   = (const float*)d_in[10];
    const float* eps  = (const float*)d_in[11];
    const float* ng   = (const float*)d_in[12];
    const float* nb   = (const float*)d_in[13];
    const float* fc1W = (const float*)d_in[14];
    const float* fc1b = (const float*)d_in[15];
    const float* n1g  = (const float*)d_in[16];
    const float* n1b  = (const float*)d_in[17];
    const float* fc2W = (const float*)d_in[18];
    const float* fc2b = (const float*)d_in[19];
    float* out = (float*)d_out;

    float* bufA = (float*)d_ws;
    float* bufB = bufA + (size_t)NN * DD;
    int* cnt     = (int*)(bufB + (size_t)NN * DD);
    int* row_ptr = cnt + NN;
    int* col     = row_ptr + NN + 2;
    int* bsum    = col + NE;

    const int nbN = (NN + 255) / 256;   // 391
    const int nbE = (NE + 255) / 256;   // 6250

    // ---- build CSR (dst-grouped) ----
    zero_int_k<<<nbN, 256, 0, stream>>>(cnt, NN);
    count_k<<<nbE, 256, 0, stream>>>(dst, cnt);
    block_reduce_k<<<nbN, 256, 0, stream>>>(cnt, bsum);
    scan_bsums_k<<<1, 64, 0, stream>>>(bsum, nbN, row_ptr);
    block_scan_k<<<nbN, 256, 0, stream>>>(cnt, bsum, row_ptr);
    zero_int_k<<<nbN, 256, 0, stream>>>(cnt, NN);
    fill_k<<<nbE, 256, 0, stream>>>(src, dst, row_ptr, cnt, col);

    const float* cur = h;
    for (int l = 0; l < NL; ++l) {
        float* x0 = (l & 1) ? bufB : bufA;
        float* x1 = (l & 1) ? bufA : bufB;
        float* nx = x0;
        agg_k<<<(NN + 7) / 8, 256, 0, stream>>>(cur, row_ptr, col, x0, eps, l);
        gemm_ln_relu_k<<<(NN + 63) / 64, 256, 0, stream>>>(
            x0, W1 + (size_t)l * DD * DD, b1 + l * DD, g1 + l * DD, be1 + l * DD, x1, NN);
        gemm_ln_relu_k<<<(NN + 63) / 64, 256, 0, stream>>>(
            x1, W2 + (size_t)l * DD * DD, b2 + l * DD, ng + l * DD, nb + l * DD, nx, NN);
        cur = nx;
    }
    head_k<<<NG, 128, 0, stream>>>(cur, gid, desc, fc1W, fc1b, n1g, n1b, fc2W, fc2b, out);
}

// Round 3
// 1108.882 us; speedup vs baseline: 7.8610x; 1.0740x over previous
//
#include <hip/hip_runtime.h>

#define NN 100000
#define NE 1600000
#define DD 128
#define NG 256
#define XX 16
#define NL 3
#define LNEPS 1e-5f

typedef _Float16 half8 __attribute__((ext_vector_type(8)));
typedef float f32x4 __attribute__((ext_vector_type(4)));

// ---------------- CSR build ----------------

__global__ __launch_bounds__(256) void zero_int_k(int* __restrict__ p, int n) {
    int i = blockIdx.x * 256 + threadIdx.x;
    if (i < n) p[i] = 0;
}

__global__ __launch_bounds__(256) void count_k(const int* __restrict__ dst,
                                               int* __restrict__ cnt) {
    int e = blockIdx.x * 256 + threadIdx.x;
    if (e < NE) atomicAdd(&cnt[dst[e]], 1);
}

__global__ __launch_bounds__(256) void block_reduce_k(const int* __restrict__ cnt,
                                                      int* __restrict__ bsum) {
    __shared__ int sw[4];
    int i = blockIdx.x * 256 + threadIdx.x;
    int v = i < NN ? cnt[i] : 0;
    #pragma unroll
    for (int m = 1; m <= 32; m <<= 1) v += __shfl_xor(v, m);
    int lane = threadIdx.x & 63, wid = threadIdx.x >> 6;
    if (lane == 0) sw[wid] = v;
    __syncthreads();
    if (threadIdx.x == 0) bsum[blockIdx.x] = sw[0] + sw[1] + sw[2] + sw[3];
}

__global__ void scan_bsums_k(int* __restrict__ bsum, int nb, int* __restrict__ row_ptr) {
    if (threadIdx.x == 0 && blockIdx.x == 0) {
        int run = 0;
        for (int i = 0; i < nb; ++i) { int v = bsum[i]; bsum[i] = run; run += v; }
        row_ptr[NN] = NE;
    }
}

__global__ __launch_bounds__(256) void block_scan_k(const int* __restrict__ cnt,
                                                    const int* __restrict__ bsum,
                                                    int* __restrict__ row_ptr) {
    __shared__ int sd[256];
    int t = threadIdx.x;
    int i = blockIdx.x * 256 + t;
    int v = i < NN ? cnt[i] : 0;
    sd[t] = v;
    __syncthreads();
    #pragma unroll
    for (int off = 1; off < 256; off <<= 1) {
        int x = t >= off ? sd[t - off] : 0;
        __syncthreads();
        sd[t] += x;
        __syncthreads();
    }
    if (i < NN) row_ptr[i] = bsum[blockIdx.x] + sd[t] - v;
}

__global__ __launch_bounds__(256) void fill_k(const int* __restrict__ src,
                                              const int* __restrict__ dst,
                                              const int* __restrict__ row_ptr,
                                              int* __restrict__ cnt,
                                              int* __restrict__ col) {
    int e = blockIdx.x * 256 + threadIdx.x;
    if (e >= NE) return;
    int d = dst[e];
    int slot = row_ptr[d] + atomicAdd(&cnt[d], 1);
    col[slot] = src[e];
}

// ---------------- pull-mode aggregation ----------------
__global__ __launch_bounds__(256) void agg_k(const float* __restrict__ h,
                                             const int* __restrict__ row_ptr,
                                             const int* __restrict__ col,
                                             float* __restrict__ x0,
                                             const float* __restrict__ eps, int l) {
    const float e = 1.0f + eps[l];
    const int v = blockIdx.x * 8 + (threadIdx.x >> 5);
    const int q = threadIdx.x & 31;
    if (v >= NN) return;
    const int lo = row_ptr[v], hi = row_ptr[v + 1];
    float4 acc = *(const float4*)&h[(size_t)v * DD + q * 4];
    acc.x *= e; acc.y *= e; acc.z *= e; acc.w *= e;
    for (int i = lo; i < hi; ++i) {
        int s = col[i];
        float4 hv = *(const float4*)&h[(size_t)s * DD + q * 4];
        acc.x += hv.x; acc.y += hv.y; acc.z += hv.z; acc.w += hv.w;
    }
    *(float4*)&x0[(size_t)v * DD + q * 4] = acc;
}

// ---------------- W split+transpose prep: wt[mtx][term][col][k] ----------------
__global__ __launch_bounds__(256) void wprep_k(const float* __restrict__ W1,
                                               const float* __restrict__ W2,
                                               _Float16* __restrict__ wt) {
    int idx = blockIdx.x * 256 + threadIdx.x;       // 6*16384
    if (idx >= 6 * 16384) return;
    int mtx = idx >> 14;
    int r = idx & 16383;                            // col*128 + k
    int c = r >> 7, k = r & 127;
    int l = mtx >> 1;
    const float* W = (mtx & 1) ? W2 : W1;
    float w = W[(size_t)l * 16384 + k * 128 + c];
    _Float16 hi = (_Float16)w;
    _Float16 lo = (_Float16)((w - (float)hi) * 2048.0f);   // scaled by 2^11
    wt[(size_t)mtx * 2 * 16384 + r] = hi;
    wt[(size_t)mtx * 2 * 16384 + 16384 + r] = lo;
}

// ---------------- MFMA GEMM: y = relu(LN(x @ W + bias)) ----------------
// fp32 via fp16 split: x*w = xh*wh + (xh*wl + xl*wh)/2048
// block 128 rows x 128 cols, 4 waves (2x2), wave tile 64x64 = 4x4 frags 16x16x32
#define LP 72   // LDS row pitch in f16 elems (64 + 8 pad)
__global__ __launch_bounds__(256) void gemm_mfma_k(const float* __restrict__ x,
                                                   const _Float16* __restrict__ wthi,
                                                   const _Float16* __restrict__ wtlo,
                                                   const float* __restrict__ bias,
                                                   const float* __restrict__ gamma,
                                                   const float* __restrict__ beta,
                                                   float* __restrict__ y, int nrows) {
    __shared__ _Float16 Ahi[128 * LP];
    __shared__ _Float16 Alo[128 * LP];
    __shared__ _Float16 Bhi[128 * LP];
    __shared__ _Float16 Blo[128 * LP];
    __shared__ float2 part[2][128];

    const int tid = threadIdx.x;
    const int wave = tid >> 6;
    const int lane = tid & 63;
    const int wr = wave >> 1, wc = wave & 1;
    const int cl = lane & 15, gq = lane >> 4;
    const int rb = blockIdx.x * 128;

    f32x4 acc[4][4] = {};
    f32x4 acc2[4][4] = {};

    for (int hf = 0; hf < 2; ++hf) {
        __syncthreads();
        // stage A: read f32, split into hi / lo*2^11 f16
        #pragma unroll
        for (int i = 0; i < 8; ++i) {
            int c = tid + 256 * i;          // 2048 chunks of 4 elems
            int row = c >> 4, kc = c & 15;
            int gr = rb + row;
            int sr = gr < nrows ? gr : 0;
            float4 v = *(const float4*)&x[(size_t)sr * DD + hf * 64 + kc * 4];
            union { _Float16 h[4]; float2 f; } ph, pl;
            ph.h[0] = (_Float16)v.x; pl.h[0] = (_Float16)((v.x - (float)ph.h[0]) * 2048.0f);
            ph.h[1] = (_Float16)v.y; pl.h[1] = (_Float16)((v.y - (float)ph.h[1]) * 2048.0f);
            ph.h[2] = (_Float16)v.z; pl.h[2] = (_Float16)((v.z - (float)ph.h[2]) * 2048.0f);
            ph.h[3] = (_Float16)v.w; pl.h[3] = (_Float16)((v.w - (float)ph.h[3]) * 2048.0f);
            *(float2*)&Ahi[row * LP + kc * 4] = ph.f;
            *(float2*)&Alo[row * LP + kc * 4] = pl.f;
        }
        // stage W^T halves (pre-split)
        #pragma unroll
        for (int i = 0; i < 4; ++i) {
            int c = tid + 256 * i;          // 1024 chunks of 8 f16
            int col = c >> 3, kc = c & 7;
            *(float4*)&Bhi[col * LP + kc * 8] =
                *(const float4*)&wthi[col * DD + hf * 64 + kc * 8];
            *(float4*)&Blo[col * LP + kc * 8] =
                *(const float4*)&wtlo[col * DD + hf * 64 + kc * 8];
        }
        __syncthreads();
        #pragma unroll
        for (int kk = 0; kk < 2; ++kk) {
            const int kof = kk * 32 + gq * 8;
            half8 ah[4], al[4], bh[4], bl[4];
            #pragma unroll
            for (int m = 0; m < 4; ++m) {
                int row = wr * 64 + m * 16 + cl;
                ah[m] = *(const half8*)&Ahi[row * LP + kof];
                al[m] = *(const half8*)&Alo[row * LP + kof];
            }
            #pragma unroll
            for (int n = 0; n < 4; ++n) {
                int col = wc * 64 + n * 16 + cl;
                bh[n] = *(const half8*)&Bhi[col * LP + kof];
                bl[n] = *(const half8*)&Blo[col * LP + kof];
            }
            #pragma unroll
            for (int m = 0; m < 4; ++m)
                #pragma unroll
                for (int n = 0; n < 4; ++n) {
                    acc[m][n]  = __builtin_amdgcn_mfma_f32_16x16x32_f16(ah[m], bh[n], acc[m][n], 0, 0, 0);
                    acc2[m][n] = __builtin_amdgcn_mfma_f32_16x16x32_f16(ah[m], bl[n], acc2[m][n], 0, 0, 0);
                    acc2[m][n] = __builtin_amdgcn_mfma_f32_16x16x32_f16(al[m], bh[n], acc2[m][n], 0, 0, 0);
                }
        }
    }

    // epilogue: z = acc + acc2/2048 + bias; LN over 128 cols; relu; store f32
    float bv[4], gv[4], bev[4];
    #pragma unroll
    for (int n = 0; n < 4; ++n) {
        int c = wc * 64 + n * 16 + cl;
        bv[n] = bias[c]; gv[n] = gamma[c]; bev[n] = beta[c];
    }
    #pragma unroll
    for (int m = 0; m < 4; ++m)
        #pragma unroll
        for (int j = 0; j < 4; ++j) {
            float s1 = 0.f, s2 = 0.f;
            #pragma unroll
            for (int n = 0; n < 4; ++n) {
                float z = acc[m][n][j] + acc2[m][n][j] * (1.0f / 2048.0f) + bv[n];
                acc[m][n][j] = z;
                s1 += z; s2 += z * z;
            }
            #pragma unroll
            for (int msk = 1; msk <= 8; msk <<= 1) {
                s1 += __shfl_xor(s1, msk);
                s2 += __shfl_xor(s2, msk);
            }
            if (cl == 0) part[wc][wr * 64 + m * 16 + gq * 4 + j] = make_float2(s1, s2);
        }
    __syncthreads();
    #pragma unroll
    for (int m = 0; m < 4; ++m)
        #pragma unroll
        for (int j = 0; j < 4; ++j) {
            int r = wr * 64 + m * 16 + gq * 4 + j;
            float2 p0 = part[0][r], p1 = part[1][r];
            float s1 = p0.x + p1.x, s2 = p0.y + p1.y;
            float mean = s1 * (1.0f / DD);
            float inv = rsqrtf(s2 * (1.0f / DD) - mean * mean + LNEPS);
            int grow = rb + r;
            if (grow < nrows) {
                #pragma unroll
                for (int n = 0; n < 4; ++n) {
                    float o = (acc[m][n][j] - mean) * inv * gv[n] + bev[n];
                    y[(size_t)grow * DD + wc * 64 + n * 16 + cl] = fmaxf(o, 0.f);
                }
            }
        }
}

__device__ __forceinline__ int lower_bound_i(const int* a, int n, int v) {
    int lo = 0, hi = n;
    while (lo < hi) { int m = (lo + hi) >> 1; if (a[m] < v) lo = m + 1; else hi = m; }
    return lo;
}

__global__ __launch_bounds__(128) void head_k(const float* __restrict__ h,
                                              const int* __restrict__ gid,
                                              const float* __restrict__ desc,
                                              const float* __restrict__ fc1W,
                                              const float* __restrict__ fc1b,
                                              const float* __restrict__ n1g,
                                              const float* __restrict__ n1b,
                                              const float* __restrict__ fc2W,
                                              const float* __restrict__ fc2b,
                                              float* __restrict__ out) {
    const int g = blockIdx.x;
    const int c = threadIdx.x;
    __shared__ float cat[DD + XX];
    __shared__ float red[4];
    int lo = lower_bound_i(gid, NN, g);
    int hi = lower_bound_i(gid, NN, g + 1);
    float s = 0.f;
    for (int i = lo; i < hi; ++i) s += h[(size_t)i * DD + c];
    cat[c] = s;
    if (c < XX) cat[DD + c] = desc[g * XX + c];
    __syncthreads();
    float z = fc1b[c];
    for (int k = 0; k < DD + XX; ++k) z += cat[k] * fc1W[k * DD + c];
    float s1 = z, s2 = z * z;
    #pragma unroll
    for (int m = 1; m <= 32; m <<= 1) { s1 += __shfl_xor(s1, m); s2 += __shfl_xor(s2, m); }
    int wid = c >> 6, lane = c & 63;
    if (lane == 0) { red[wid] = s1; red[2 + wid] = s2; }
    __syncthreads();
    s1 = red[0] + red[1]; s2 = red[2] + red[3];
    float mean = s1 * (1.0f / DD);
    float var  = s2 * (1.0f / DD) - mean * mean;
    float inv  = rsqrtf(var + LNEPS);
    float zr = fmaxf((z - mean) * inv * n1g[c] + n1b[c], 0.f);
    float p = zr * fc2W[c];
    #pragma unroll
    for (int m = 1; m <= 32; m <<= 1) p += __shfl_xor(p, m);
    __syncthreads();
    if (lane == 0) red[wid] = p;
    __syncthreads();
    if (c == 0) out[g] = red[0] + red[1] + fc2b[0];
}

extern "C" void kernel_launch(void* const* d_in, const int* in_sizes, int n_in,
                              void* d_out, int out_size, void* d_ws, size_t ws_size,
                              hipStream_t stream) {
    const float* h    = (const float*)d_in[0];
    const float* desc = (const float*)d_in[1];
    const int*   src  = (const int*)d_in[2];
    const int*   dst  = (const int*)d_in[3];
    const int*   gid  = (const int*)d_in[4];
    const float* W1   = (const float*)d_in[5];
    const float* b1   = (const float*)d_in[6];
    const float* g1   = (const float*)d_in[7];
    const float* be1  = (const float*)d_in[8];
    const float* W2   = (const float*)d_in[9];
    const float* b2   = (const float*)d_in[10];
    const float* eps  = (const float*)d_in[11];
    const float* ng   = (const float*)d_in[12];
    const float* nb   = (const float*)d_in[13];
    const float* fc1W = (const float*)d_in[14];
    const float* fc1b = (const float*)d_in[15];
    const float* n1g  = (const float*)d_in[16];
    const float* n1b  = (const float*)d_in[17];
    const float* fc2W = (const float*)d_in[18];
    const float* fc2b = (const float*)d_in[19];
    float* out = (float*)d_out;

    float* bufA = (float*)d_ws;
    float* bufB = bufA + (size_t)NN * DD;
    int* cnt     = (int*)(bufB + (size_t)NN * DD);
    int* row_ptr = cnt + NN;
    int* col     = row_ptr + NN + 4;
    int* bsum    = col + NE;
    _Float16* wt = (_Float16*)(((uintptr_t)(bsum + 512) + 255) & ~(uintptr_t)255);

    const int nbN = (NN + 255) / 256;
    const int nbE = (NE + 255) / 256;

    wprep_k<<<(6 * 16384 + 255) / 256, 256, 0, stream>>>(W1, W2, wt);

    zero_int_k<<<nbN, 256, 0, stream>>>(cnt, NN);
    count_k<<<nbE, 256, 0, stream>>>(dst, cnt);
    block_reduce_k<<<nbN, 256, 0, stream>>>(cnt, bsum);
    scan_bsums_k<<<1, 64, 0, stream>>>(bsum, nbN, row_ptr);
    block_scan_k<<<nbN, 256, 0, stream>>>(cnt, bsum, row_ptr);
    zero_int_k<<<nbN, 256, 0, stream>>>(cnt, NN);
    fill_k<<<nbE, 256, 0, stream>>>(src, dst, row_ptr, cnt, col);

    const int gemm_grid = (NN + 127) / 128;
    const float* cur = h;
    for (int l = 0; l < NL; ++l) {
        float* x0 = (l & 1) ? bufB : bufA;
        float* x1 = (l & 1) ? bufA : bufB;
        float* nx = x0;
        const _Float16* w1hi = wt + (size_t)(l * 2 + 0) * 2 * 16384;
        const _Float16* w1lo = w1hi + 16384;
        const _Float16* w2hi = wt + (size_t)(l * 2 + 1) * 2 * 16384;
        const _Float16* w2lo = w2hi + 16384;
        agg_k<<<(NN + 7) / 8, 256, 0, stream>>>(cur, row_ptr, col, x0, eps, l);
        gemm_mfma_k<<<gemm_grid, 256, 0, stream>>>(
            x0, w1hi, w1lo, b1 + l * DD, g1 + l * DD, be1 + l * DD, x1, NN);
        gemm_mfma_k<<<gemm_grid, 256, 0, stream>>>(
            x1, w2hi, w2lo, b2 + l * DD, ng + l * DD, nb + l * DD, nx, NN);
        cur = nx;
    }
    head_k<<<NG, 128, 0, stream>>>(cur, gid, desc, fc1W, fc1b, n1g, n1b, fc2W, fc2b, out);
}

// Round 4
// 1019.768 us; speedup vs baseline: 8.5479x; 1.0874x over previous
//
#include <hip/hip_runtime.h>

#define NN 100000
#define NE 1600000
#define DD 128
#define NG 256
#define XX 16
#define NL 3
#define LNEPS 1e-5f

typedef _Float16 half8 __attribute__((ext_vector_type(8)));
typedef float f32x4 __attribute__((ext_vector_type(4)));

// ---------------- CSR build ----------------

__global__ __launch_bounds__(256) void zero_int_k(int* __restrict__ p, int n) {
    int i = blockIdx.x * 256 + threadIdx.x;
    if (i < n) p[i] = 0;
}

__global__ __launch_bounds__(256) void count_k(const int* __restrict__ dst,
                                               int* __restrict__ cnt) {
    int e = blockIdx.x * 256 + threadIdx.x;
    if (e < NE) atomicAdd(&cnt[dst[e]], 1);
}

__global__ __launch_bounds__(256) void block_reduce_k(const int* __restrict__ cnt,
                                                      int* __restrict__ bsum) {
    __shared__ int sw[4];
    int i = blockIdx.x * 256 + threadIdx.x;
    int v = i < NN ? cnt[i] : 0;
    #pragma unroll
    for (int m = 1; m <= 32; m <<= 1) v += __shfl_xor(v, m);
    int lane = threadIdx.x & 63, wid = threadIdx.x >> 6;
    if (lane == 0) sw[wid] = v;
    __syncthreads();
    if (threadIdx.x == 0) bsum[blockIdx.x] = sw[0] + sw[1] + sw[2] + sw[3];
}

// parallel exclusive scan of block sums (nb <= 512), single block
__global__ __launch_bounds__(512) void scan_bsums2_k(int* __restrict__ bsum, int nb,
                                                     int* __restrict__ row_ptr) {
    __shared__ int sd[512];
    int t = threadIdx.x;
    int v = t < nb ? bsum[t] : 0;
    sd[t] = v;
    __syncthreads();
    #pragma unroll
    for (int off = 1; off < 512; off <<= 1) {
        int x = t >= off ? sd[t - off] : 0;
        __syncthreads();
        sd[t] += x;
        __syncthreads();
    }
    if (t < nb) bsum[t] = sd[t] - v;   // exclusive
    if (t == 0) row_ptr[NN] = NE;
}

__global__ __launch_bounds__(256) void block_scan_k(const int* __restrict__ cnt,
                                                    const int* __restrict__ bsum,
                                                    int* __restrict__ row_ptr) {
    __shared__ int sd[256];
    int t = threadIdx.x;
    int i = blockIdx.x * 256 + t;
    int v = i < NN ? cnt[i] : 0;
    sd[t] = v;
    __syncthreads();
    #pragma unroll
    for (int off = 1; off < 256; off <<= 1) {
        int x = t >= off ? sd[t - off] : 0;
        __syncthreads();
        sd[t] += x;
        __syncthreads();
    }
    if (i < NN) row_ptr[i] = bsum[blockIdx.x] + sd[t] - v;
}

// rank via atomicSub on existing counts (no re-zero pass needed)
__global__ __launch_bounds__(256) void fill_k(const int* __restrict__ src,
                                              const int* __restrict__ dst,
                                              const int* __restrict__ row_ptr,
                                              int* __restrict__ cnt,
                                              int* __restrict__ col) {
    int e = blockIdx.x * 256 + threadIdx.x;
    if (e >= NE) return;
    int d = dst[e];
    int r = atomicSub(&cnt[d], 1) - 1;
    __builtin_nontemporal_store(src[e], &col[row_ptr[d] + r]);
}

// ---------------- aggregation: out = split_f16( (1+eps)*h[v] + sum h[u] ) ----------------
__global__ __launch_bounds__(256) void agg_k(const float* __restrict__ h,
                                             const int* __restrict__ row_ptr,
                                             const int* __restrict__ col,
                                             _Float16* __restrict__ xhi,
                                             _Float16* __restrict__ xlo,
                                             const float* __restrict__ eps, int l) {
    const float e = 1.0f + eps[l];
    const int v = blockIdx.x * 8 + (threadIdx.x >> 5);
    const int q = threadIdx.x & 31;
    if (v >= NN) return;
    const int lo = row_ptr[v], hi = row_ptr[v + 1];
    float4 a0 = *(const float4*)&h[(size_t)v * DD + q * 4];
    a0.x *= e; a0.y *= e; a0.z *= e; a0.w *= e;
    float4 a1 = make_float4(0.f, 0.f, 0.f, 0.f);
    int i = lo;
    for (; i + 4 <= hi; i += 4) {
        int s0 = col[i], s1 = col[i + 1], s2 = col[i + 2], s3 = col[i + 3];
        float4 v0 = *(const float4*)&h[(size_t)s0 * DD + q * 4];
        float4 v1 = *(const float4*)&h[(size_t)s1 * DD + q * 4];
        float4 v2 = *(const float4*)&h[(size_t)s2 * DD + q * 4];
        float4 v3 = *(const float4*)&h[(size_t)s3 * DD + q * 4];
        a0.x += v0.x + v1.x; a0.y += v0.y + v1.y; a0.z += v0.z + v1.z; a0.w += v0.w + v1.w;
        a1.x += v2.x + v3.x; a1.y += v2.y + v3.y; a1.z += v2.z + v3.z; a1.w += v2.w + v3.w;
    }
    for (; i < hi; ++i) {
        int s = col[i];
        float4 hv = *(const float4*)&h[(size_t)s * DD + q * 4];
        a0.x += hv.x; a0.y += hv.y; a0.z += hv.z; a0.w += hv.w;
    }
    a0.x += a1.x; a0.y += a1.y; a0.z += a1.z; a0.w += a1.w;
    union { _Float16 hh[4]; float2 f; } ph, pl;
    ph.hh[0] = (_Float16)a0.x; pl.hh[0] = (_Float16)((a0.x - (float)ph.hh[0]) * 2048.0f);
    ph.hh[1] = (_Float16)a0.y; pl.hh[1] = (_Float16)((a0.y - (float)ph.hh[1]) * 2048.0f);
    ph.hh[2] = (_Float16)a0.z; pl.hh[2] = (_Float16)((a0.z - (float)ph.hh[2]) * 2048.0f);
    ph.hh[3] = (_Float16)a0.w; pl.hh[3] = (_Float16)((a0.w - (float)ph.hh[3]) * 2048.0f);
    *(float2*)&xhi[(size_t)v * DD + q * 4] = ph.f;
    *(float2*)&xlo[(size_t)v * DD + q * 4] = pl.f;
}

// ---------------- W split+transpose prep: wt[mtx][term][col][k] ----------------
__global__ __launch_bounds__(256) void wprep_k(const float* __restrict__ W1,
                                               const float* __restrict__ W2,
                                               _Float16* __restrict__ wt) {
    int idx = blockIdx.x * 256 + threadIdx.x;
    if (idx >= 6 * 16384) return;
    int mtx = idx >> 14;
    int r = idx & 16383;                            // col*128 + k
    int c = r >> 7, k = r & 127;
    int l = mtx >> 1;
    const float* W = (mtx & 1) ? W2 : W1;
    float w = W[(size_t)l * 16384 + k * 128 + c];
    _Float16 hi = (_Float16)w;
    _Float16 lo = (_Float16)((w - (float)hi) * 2048.0f);
    wt[(size_t)mtx * 2 * 16384 + r] = hi;
    wt[(size_t)mtx * 2 * 16384 + 16384 + r] = lo;
}

// ---------------- MFMA GEMM: y = relu(LN(x @ W + b)); pre-split inputs ----------------
// block: 64 rows x 128 cols, 4 waves (each 64x32); A in LDS, B in regs (dbuf from L2)
#define LPA 72
__global__ __launch_bounds__(256) void gemm_mfma_k(const _Float16* __restrict__ xhi,
                                                   const _Float16* __restrict__ xlo,
                                                   const _Float16* __restrict__ wthi,
                                                   const _Float16* __restrict__ wtlo,
                                                   const float* __restrict__ bias,
                                                   const float* __restrict__ gamma,
                                                   const float* __restrict__ beta,
                                                   _Float16* __restrict__ yhi,
                                                   _Float16* __restrict__ ylo,
                                                   float* __restrict__ yf,
                                                   int mode, int nrows) {
    __shared__ _Float16 Ahi[64 * LPA];
    __shared__ _Float16 Alo[64 * LPA];
    __shared__ float2 part[4][64];

    const int tid = threadIdx.x;
    const int wc = tid >> 6;            // col strip (32 cols)
    const int lane = tid & 63;
    const int cl = lane & 15, gq = lane >> 4;
    const int rb = blockIdx.x * 64;
    const int colbase = wc * 32;

    f32x4 acc[4][2] = {};
    f32x4 acc2[4][2] = {};

    half8 b0h[2], b0l[2], b1h[2], b1l[2];
    #pragma unroll
    for (int n = 0; n < 2; ++n) {
        int c = colbase + n * 16 + cl;
        b0h[n] = *(const half8*)&wthi[(size_t)c * DD + gq * 8];
        b0l[n] = *(const half8*)&wtlo[(size_t)c * DD + gq * 8];
    }

    #pragma unroll
    for (int hf = 0; hf < 2; ++hf) {
        __syncthreads();
        #pragma unroll
        for (int i = 0; i < 2; ++i) {
            int c = tid + 256 * i;          // 512 chunks of 8 f16
            int row = c >> 3, kc = c & 7;
            int gr = rb + row;
            int sr = gr < nrows ? gr : 0;
            *(float4*)&Ahi[row * LPA + kc * 8] =
                *(const float4*)&xhi[(size_t)sr * DD + hf * 64 + kc * 8];
            *(float4*)&Alo[row * LPA + kc * 8] =
                *(const float4*)&xlo[(size_t)sr * DD + hf * 64 + kc * 8];
        }
        __syncthreads();
        #pragma unroll
        for (int kk = 0; kk < 2; ++kk) {
            const int kt = hf * 2 + kk;     // compile-time after unroll
            if (kt < 3) {                   // prefetch next K-chunk of B into other buf
                #pragma unroll
                for (int n = 0; n < 2; ++n) {
                    int c = colbase + n * 16 + cl;
                    if ((kt & 1) == 0) {
                        b1h[n] = *(const half8*)&wthi[(size_t)c * DD + (kt + 1) * 32 + gq * 8];
                        b1l[n] = *(const half8*)&wtlo[(size_t)c * DD + (kt + 1) * 32 + gq * 8];
                    } else {
                        b0h[n] = *(const half8*)&wthi[(size_t)c * DD + (kt + 1) * 32 + gq * 8];
                        b0l[n] = *(const half8*)&wtlo[(size_t)c * DD + (kt + 1) * 32 + gq * 8];
                    }
                }
            }
            const int kof = kk * 32 + gq * 8;
            half8 ah[4], al[4];
            #pragma unroll
            for (int m = 0; m < 4; ++m) {
                int row = m * 16 + cl;
                ah[m] = *(const half8*)&Ahi[row * LPA + kof];
                al[m] = *(const half8*)&Alo[row * LPA + kof];
            }
            #pragma unroll
            for (int m = 0; m < 4; ++m)
                #pragma unroll
                for (int n = 0; n < 2; ++n) {
                    half8 bh = (kt & 1) ? b1h[n] : b0h[n];
                    half8 bl = (kt & 1) ? b1l[n] : b0l[n];
                    acc[m][n]  = __builtin_amdgcn_mfma_f32_16x16x32_f16(ah[m], bh, acc[m][n], 0, 0, 0);
                    acc2[m][n] = __builtin_amdgcn_mfma_f32_16x16x32_f16(ah[m], bl, acc2[m][n], 0, 0, 0);
                    acc2[m][n] = __builtin_amdgcn_mfma_f32_16x16x32_f16(al[m], bh, acc2[m][n], 0, 0, 0);
                }
        }
    }

    float bv[2], gv[2], bev[2];
    #pragma unroll
    for (int n = 0; n < 2; ++n) {
        int c = colbase + n * 16 + cl;
        bv[n] = bias[c]; gv[n] = gamma[c]; bev[n] = beta[c];
    }
    #pragma unroll
    for (int m = 0; m < 4; ++m)
        #pragma unroll
        for (int j = 0; j < 4; ++j) {
            float s1 = 0.f, s2 = 0.f;
            #pragma unroll
            for (int n = 0; n < 2; ++n) {
                float z = acc[m][n][j] + acc2[m][n][j] * (1.0f / 2048.0f) + bv[n];
                acc[m][n][j] = z;
                s1 += z; s2 += z * z;
            }
            #pragma unroll
            for (int msk = 1; msk <= 8; msk <<= 1) {
                s1 += __shfl_xor(s1, msk);
                s2 += __shfl_xor(s2, msk);
            }
            if (cl == 0) part[wc][m * 16 + gq * 4 + j] = make_float2(s1, s2);
        }
    __syncthreads();
    #pragma unroll
    for (int m = 0; m < 4; ++m)
        #pragma unroll
        for (int j = 0; j < 4; ++j) {
            int r = m * 16 + gq * 4 + j;
            float2 p0 = part[0][r], p1 = part[1][r], p2 = part[2][r], p3 = part[3][r];
            float s1 = p0.x + p1.x + p2.x + p3.x;
            float s2 = p0.y + p1.y + p2.y + p3.y;
            float mean = s1 * (1.0f / DD);
            float inv = rsqrtf(s2 * (1.0f / DD) - mean * mean + LNEPS);
            int grow = rb + r;
            if (grow < nrows) {
                #pragma unroll
                for (int n = 0; n < 2; ++n) {
                    float o = fmaxf((acc[m][n][j] - mean) * inv * gv[n] + bev[n], 0.f);
                    int c = colbase + n * 16 + cl;
                    if (mode == 0) {
                        _Float16 oh = (_Float16)o;
                        _Float16 ol = (_Float16)((o - (float)oh) * 2048.0f);
                        yhi[(size_t)grow * DD + c] = oh;
                        ylo[(size_t)grow * DD + c] = ol;
                    } else {
                        yf[(size_t)grow * DD + c] = o;
                    }
                }
            }
        }
}

// ---------------- pooling: run-tracked partial sums + atomic flush ----------------
__global__ __launch_bounds__(256) void pool_k(const float* __restrict__ h,
                                              const int* __restrict__ gid,
                                              float* __restrict__ hg) {
    const int c = threadIdx.x & 127;
    const int half = threadIdx.x >> 7;
    int base = blockIdx.x * 128 + half * 64;
    if (base >= NN) return;
    int end = base + 64; if (end > NN) end = NN;
    float acc = 0.f;
    int cg = gid[base];
    for (int n = base; n < end; ++n) {
        int g = gid[n];
        if (g != cg) {
            unsafeAtomicAdd(&hg[cg * DD + c], acc);
            acc = 0.f; cg = g;
        }
        acc += h[(size_t)n * DD + c];
    }
    unsafeAtomicAdd(&hg[cg * DD + c], acc);
}

// ---------------- head MLP on pooled hg ----------------
__global__ __launch_bounds__(128) void head2_k(const float* __restrict__ hg,
                                               const float* __restrict__ desc,
                                               const float* __restrict__ fc1W,
                                               const float* __restrict__ fc1b,
                                               const float* __restrict__ n1g,
                                               const float* __restrict__ n1b,
                                               const float* __restrict__ fc2W,
                                               const float* __restrict__ fc2b,
                                               float* __restrict__ out) {
    const int g = blockIdx.x;
    const int c = threadIdx.x;
    __shared__ float cat[DD + XX];
    __shared__ float red[4];
    cat[c] = hg[g * DD + c];
    if (c < XX) cat[DD + c] = desc[g * XX + c];
    __syncthreads();
    float z = fc1b[c];
    for (int k = 0; k < DD + XX; ++k) z += cat[k] * fc1W[k * DD + c];
    float s1 = z, s2 = z * z;
    #pragma unroll
    for (int m = 1; m <= 32; m <<= 1) { s1 += __shfl_xor(s1, m); s2 += __shfl_xor(s2, m); }
    int wid = c >> 6, lane = c & 63;
    if (lane == 0) { red[wid] = s1; red[2 + wid] = s2; }
    __syncthreads();
    s1 = red[0] + red[1]; s2 = red[2] + red[3];
    float mean = s1 * (1.0f / DD);
    float var  = s2 * (1.0f / DD) - mean * mean;
    float inv  = rsqrtf(var + LNEPS);
    float zr = fmaxf((z - mean) * inv * n1g[c] + n1b[c], 0.f);
    float p = zr * fc2W[c];
    #pragma unroll
    for (int m = 1; m <= 32; m <<= 1) p += __shfl_xor(p, m);
    __syncthreads();
    if (lane == 0) red[wid] = p;
    __syncthreads();
    if (c == 0) out[g] = red[0] + red[1] + fc2b[0];
}

extern "C" void kernel_launch(void* const* d_in, const int* in_sizes, int n_in,
                              void* d_out, int out_size, void* d_ws, size_t ws_size,
                              hipStream_t stream) {
    const float* h    = (const float*)d_in[0];
    const float* desc = (const float*)d_in[1];
    const int*   src  = (const int*)d_in[2];
    const int*   dst  = (const int*)d_in[3];
    const int*   gid  = (const int*)d_in[4];
    const float* W1   = (const float*)d_in[5];
    const float* b1   = (const float*)d_in[6];
    const float* g1   = (const float*)d_in[7];
    const float* be1  = (const float*)d_in[8];
    const float* W2   = (const float*)d_in[9];
    const float* b2   = (const float*)d_in[10];
    const float* eps  = (const float*)d_in[11];
    const float* ng   = (const float*)d_in[12];
    const float* nb   = (const float*)d_in[13];
    const float* fc1W = (const float*)d_in[14];
    const float* fc1b = (const float*)d_in[15];
    const float* n1g  = (const float*)d_in[16];
    const float* n1b  = (const float*)d_in[17];
    const float* fc2W = (const float*)d_in[18];
    const float* fc2b = (const float*)d_in[19];
    float* out = (float*)d_out;

    float* nx = (float*)d_ws;                         // NN*DD f32
    _Float16* XAhi = (_Float16*)(nx + (size_t)NN * DD);
    _Float16* XAlo = XAhi + (size_t)NN * DD;
    float* hg = (float*)(XAlo + (size_t)NN * DD);     // NG*DD
    int* cnt     = (int*)(hg + (size_t)NG * DD);
    int* row_ptr = cnt + NN;
    int* col     = row_ptr + NN + 4;
    int* bsum    = col + NE;
    _Float16* wt = (_Float16*)(((uintptr_t)(bsum + 512) + 255) & ~(uintptr_t)255);

    const int nbN = (NN + 255) / 256;   // 391
    const int nbE = (NE + 255) / 256;   // 6250

    wprep_k<<<(6 * 16384 + 255) / 256, 256, 0, stream>>>(W1, W2, wt);

    zero_int_k<<<nbN, 256, 0, stream>>>(cnt, NN);
    count_k<<<nbE, 256, 0, stream>>>(dst, cnt);
    block_reduce_k<<<nbN, 256, 0, stream>>>(cnt, bsum);
    scan_bsums2_k<<<1, 512, 0, stream>>>(bsum, nbN, row_ptr);
    block_scan_k<<<nbN, 256, 0, stream>>>(cnt, bsum, row_ptr);
    fill_k<<<nbE, 256, 0, stream>>>(src, dst, row_ptr, cnt, col);

    const int gemm_grid = (NN + 63) / 64;   // 1563
    const float* cur = h;
    for (int l = 0; l < NL; ++l) {
        const _Float16* w1hi = wt + (size_t)(l * 2 + 0) * 2 * 16384;
        const _Float16* w1lo = w1hi + 16384;
        const _Float16* w2hi = wt + (size_t)(l * 2 + 1) * 2 * 16384;
        const _Float16* w2lo = w2hi + 16384;
        agg_k<<<(NN + 7) / 8, 256, 0, stream>>>(cur, row_ptr, col, XAhi, XAlo, eps, l);
        // in-place: each block reads only its own rows before writing them
        gemm_mfma_k<<<gemm_grid, 256, 0, stream>>>(
            XAhi, XAlo, w1hi, w1lo, b1 + l * DD, g1 + l * DD, be1 + l * DD,
            XAhi, XAlo, nullptr, 0, NN);
        gemm_mfma_k<<<gemm_grid, 256, 0, stream>>>(
            XAhi, XAlo, w2hi, w2lo, b2 + l * DD, ng + l * DD, nb + l * DD,
            nullptr, nullptr, nx, 1, NN);
        cur = nx;
    }
    zero_int_k<<<(NG * DD + 255) / 256, 256, 0, stream>>>((int*)hg, NG * DD);
    pool_k<<<(NN + 127) / 128, 256, 0, stream>>>(cur, gid, hg);
    head2_k<<<NG, 128, 0, stream>>>(hg, desc, fc1W, fc1b, n1g, n1b, fc2W, fc2b, out);
}

// Round 5
// 842.727 us; speedup vs baseline: 10.3437x; 1.2101x over previous
//
#include <hip/hip_runtime.h>

#define NN 100000
#define NE 1600000
#define DD 128
#define NG 256
#define XX 16
#define NL 3
#define NBK 391          // buckets of 256 dst each
#define LNEPS 1e-5f

typedef _Float16 half8 __attribute__((ext_vector_type(8)));
typedef float f32x4 __attribute__((ext_vector_type(4)));

// ---------------- bucket-sorted CSR build ----------------
// Phase 1: per-block histogram of dst>>8 into hist[bucket][blk]
__global__ __launch_bounds__(256) void hist_k(const int* __restrict__ dst,
                                              int* __restrict__ hist) {
    __shared__ int lh[NBK];
    const int t = threadIdx.x, blk = blockIdx.x;
    for (int i = t; i < NBK; i += 256) lh[i] = 0;
    __syncthreads();
    const int base = blk * (NE / 256);
    for (int e = base + t; e < base + NE / 256; e += 256)
        atomicAdd(&lh[dst[e] >> 8], 1);
    __syncthreads();
    for (int i = t; i < NBK; i += 256) hist[i * 256 + blk] = lh[i];
}

// Phase 2a: within-bucket exclusive prefix over the 256 blocks; bucket total -> btot
__global__ __launch_bounds__(256) void bucketpref_k(int* __restrict__ hist,
                                                    int* __restrict__ btot) {
    __shared__ int sd[256];
    const int b = blockIdx.x, t = threadIdx.x;
    int v = hist[b * 256 + t];
    sd[t] = v;
    __syncthreads();
    #pragma unroll
    for (int off = 1; off < 256; off <<= 1) {
        int x = t >= off ? sd[t - off] : 0;
        __syncthreads();
        sd[t] += x;
        __syncthreads();
    }
    hist[b * 256 + t] = sd[t] - v;      // exclusive within bucket
    if (t == 255) btot[b] = sd[255];    // bucket total
}

// Phase 2b: exclusive scan of bucket totals (nb <= 512)
__global__ __launch_bounds__(512) void scan_bsums2_k(int* __restrict__ bsum, int nb,
                                                     int* __restrict__ row_ptr) {
    __shared__ int sd[512];
    int t = threadIdx.x;
    int v = t < nb ? bsum[t] : 0;
    sd[t] = v;
    __syncthreads();
    #pragma unroll
    for (int off = 1; off < 512; off <<= 1) {
        int x = t >= off ? sd[t - off] : 0;
        __syncthreads();
        sd[t] += x;
        __syncthreads();
    }
    if (t < nb) bsum[t] = sd[t] - v;   // exclusive base
    if (t == 0) row_ptr[NN] = NE;
}

// Phase 3: scatter (src,dst) pairs bucket-contiguously
__global__ __launch_bounds__(256) void scatter_pairs_k(const int* __restrict__ src,
                                                       const int* __restrict__ dst,
                                                       const int* __restrict__ btot,
                                                       const int* __restrict__ hist,
                                                       int2* __restrict__ pairs) {
    __shared__ int off[NBK];
    const int t = threadIdx.x, blk = blockIdx.x;
    for (int i = t; i < NBK; i += 256)
        off[i] = btot[i] + hist[i * 256 + blk];
    __syncthreads();
    const int base = blk * (NE / 256);
    for (int e = base + t; e < base + NE / 256; e += 256) {
        int d = dst[e];
        int pos = atomicAdd(&off[d >> 8], 1);
        pairs[pos] = make_int2(src[e], d);
    }
}

// Phase 4: one block per bucket -> local CSR slice (row_ptr + col)
__global__ __launch_bounds__(256) void bucket_csr_k(const int2* __restrict__ pairs,
                                                    const int* __restrict__ btot,
                                                    int* __restrict__ row_ptr,
                                                    int* __restrict__ col) {
    __shared__ int cntL[256], ex[256], rnk[256], sd[256];
    const int b = blockIdx.x, t = threadIdx.x;
    const int nbase = b << 8;
    const int ps = btot[b];
    const int pe = (b == NBK - 1) ? NE : btot[b + 1];
    cntL[t] = 0; rnk[t] = 0;
    __syncthreads();
    for (int i = ps + t; i < pe; i += 256)
        atomicAdd(&cntL[pairs[i].y - nbase], 1);
    __syncthreads();
    int v = cntL[t];
    sd[t] = v;
    __syncthreads();
    #pragma unroll
    for (int off = 1; off < 256; off <<= 1) {
        int x = t >= off ? sd[t - off] : 0;
        __syncthreads();
        sd[t] += x;
        __syncthreads();
    }
    ex[t] = sd[t] - v;
    int node = nbase + t;
    if (node < NN) row_ptr[node] = ps + ex[t];
    __syncthreads();
    for (int i = ps + t; i < pe; i += 256) {
        int2 p = pairs[i];
        int li = p.y - nbase;
        int r = atomicAdd(&rnk[li], 1);
        col[ps + ex[li] + r] = p.x;
    }
}

// ---------------- aggregation: out = split_f16( (1+eps)*h[v] + sum h[u] ) ----------------
__global__ __launch_bounds__(256) void agg_k(const float* __restrict__ h,
                                             const int* __restrict__ row_ptr,
                                             const int* __restrict__ col,
                                             _Float16* __restrict__ xhi,
                                             _Float16* __restrict__ xlo,
                                             const float* __restrict__ eps, int l) {
    const float e = 1.0f + eps[l];
    const int v = blockIdx.x * 8 + (threadIdx.x >> 5);
    const int q = threadIdx.x & 31;
    if (v >= NN) return;
    const int lo = row_ptr[v], hi = row_ptr[v + 1];
    float4 a0 = *(const float4*)&h[(size_t)v * DD + q * 4];
    a0.x *= e; a0.y *= e; a0.z *= e; a0.w *= e;
    float4 a1 = make_float4(0.f, 0.f, 0.f, 0.f);
    float4 a2 = make_float4(0.f, 0.f, 0.f, 0.f);
    float4 a3 = make_float4(0.f, 0.f, 0.f, 0.f);
    int i = lo;
    for (; i + 8 <= hi; i += 8) {
        int s0 = col[i],     s1 = col[i + 1], s2 = col[i + 2], s3 = col[i + 3];
        int s4 = col[i + 4], s5 = col[i + 5], s6 = col[i + 6], s7 = col[i + 7];
        float4 v0 = *(const float4*)&h[(size_t)s0 * DD + q * 4];
        float4 v1 = *(const float4*)&h[(size_t)s1 * DD + q * 4];
        float4 v2 = *(const float4*)&h[(size_t)s2 * DD + q * 4];
        float4 v3 = *(const float4*)&h[(size_t)s3 * DD + q * 4];
        float4 v4 = *(const float4*)&h[(size_t)s4 * DD + q * 4];
        float4 v5 = *(const float4*)&h[(size_t)s5 * DD + q * 4];
        float4 v6 = *(const float4*)&h[(size_t)s6 * DD + q * 4];
        float4 v7 = *(const float4*)&h[(size_t)s7 * DD + q * 4];
        a0.x += v0.x; a0.y += v0.y; a0.z += v0.z; a0.w += v0.w;
        a1.x += v1.x; a1.y += v1.y; a1.z += v1.z; a1.w += v1.w;
        a2.x += v2.x; a2.y += v2.y; a2.z += v2.z; a2.w += v2.w;
        a3.x += v3.x; a3.y += v3.y; a3.z += v3.z; a3.w += v3.w;
        a0.x += v4.x; a0.y += v4.y; a0.z += v4.z; a0.w += v4.w;
        a1.x += v5.x; a1.y += v5.y; a1.z += v5.z; a1.w += v5.w;
        a2.x += v6.x; a2.y += v6.y; a2.z += v6.z; a2.w += v6.w;
        a3.x += v7.x; a3.y += v7.y; a3.z += v7.z; a3.w += v7.w;
    }
    for (; i + 2 <= hi; i += 2) {
        int s0 = col[i], s1 = col[i + 1];
        float4 v0 = *(const float4*)&h[(size_t)s0 * DD + q * 4];
        float4 v1 = *(const float4*)&h[(size_t)s1 * DD + q * 4];
        a0.x += v0.x; a0.y += v0.y; a0.z += v0.z; a0.w += v0.w;
        a1.x += v1.x; a1.y += v1.y; a1.z += v1.z; a1.w += v1.w;
    }
    if (i < hi) {
        int s = col[i];
        float4 hv = *(const float4*)&h[(size_t)s * DD + q * 4];
        a0.x += hv.x; a0.y += hv.y; a0.z += hv.z; a0.w += hv.w;
    }
    a0.x += a1.x + a2.x + a3.x;
    a0.y += a1.y + a2.y + a3.y;
    a0.z += a1.z + a2.z + a3.z;
    a0.w += a1.w + a2.w + a3.w;
    union { _Float16 hh[4]; float2 f; } ph, pl;
    ph.hh[0] = (_Float16)a0.x; pl.hh[0] = (_Float16)((a0.x - (float)ph.hh[0]) * 2048.0f);
    ph.hh[1] = (_Float16)a0.y; pl.hh[1] = (_Float16)((a0.y - (float)ph.hh[1]) * 2048.0f);
    ph.hh[2] = (_Float16)a0.z; pl.hh[2] = (_Float16)((a0.z - (float)ph.hh[2]) * 2048.0f);
    ph.hh[3] = (_Float16)a0.w; pl.hh[3] = (_Float16)((a0.w - (float)ph.hh[3]) * 2048.0f);
    *(float2*)&xhi[(size_t)v * DD + q * 4] = ph.f;
    *(float2*)&xlo[(size_t)v * DD + q * 4] = pl.f;
}

// ---------------- W split+transpose prep ----------------
__global__ __launch_bounds__(256) void wprep_k(const float* __restrict__ W1,
                                               const float* __restrict__ W2,
                                               _Float16* __restrict__ wt) {
    int idx = blockIdx.x * 256 + threadIdx.x;
    if (idx >= 6 * 16384) return;
    int mtx = idx >> 14;
    int r = idx & 16383;                            // col*128 + k
    int c = r >> 7, k = r & 127;
    int l = mtx >> 1;
    const float* W = (mtx & 1) ? W2 : W1;
    float w = W[(size_t)l * 16384 + k * 128 + c];
    _Float16 hi = (_Float16)w;
    _Float16 lo = (_Float16)((w - (float)hi) * 2048.0f);
    wt[(size_t)mtx * 2 * 16384 + r] = hi;
    wt[(size_t)mtx * 2 * 16384 + 16384 + r] = lo;
}

// ---------------- MFMA GEMM: y = relu(LN(x @ W + b)); single-stage LDS ----------------
#define LP2 136
__global__ __launch_bounds__(256) void gemm_mfma_k(const _Float16* __restrict__ xhi,
                                                   const _Float16* __restrict__ xlo,
                                                   const _Float16* __restrict__ wthi,
                                                   const _Float16* __restrict__ wtlo,
                                                   const float* __restrict__ bias,
                                                   const float* __restrict__ gamma,
                                                   const float* __restrict__ beta,
                                                   _Float16* __restrict__ yhi,
                                                   _Float16* __restrict__ ylo,
                                                   float* __restrict__ yf,
                                                   int mode, int nrows) {
    __shared__ _Float16 Ahi[64 * LP2];
    __shared__ _Float16 Alo[64 * LP2];
    __shared__ float2 part[4][64];

    const int tid = threadIdx.x;
    const int wc = tid >> 6;            // col strip (32 cols)
    const int lane = tid & 63;
    const int cl = lane & 15, gq = lane >> 4;
    const int rb = blockIdx.x * 64;
    const int colbase = wc * 32;

    f32x4 acc[4][2] = {};
    f32x4 acc2[4][2] = {};

    // stage full 64x128 A (hi+lo): 1024 chunks of 8 f16 each
    #pragma unroll
    for (int i = 0; i < 4; ++i) {
        int c = tid + 256 * i;
        int row = c >> 4, kc = c & 15;
        int gr = rb + row;
        int sr = gr < nrows ? gr : 0;
        *(float4*)&Ahi[row * LP2 + kc * 8] =
            *(const float4*)&xhi[(size_t)sr * DD + kc * 8];
        *(float4*)&Alo[row * LP2 + kc * 8] =
            *(const float4*)&xlo[(size_t)sr * DD + kc * 8];
    }
    __syncthreads();

    #pragma unroll
    for (int kt = 0; kt < 4; ++kt) {
        half8 bh[2], bl[2], ah[4], al[4];
        #pragma unroll
        for (int n = 0; n < 2; ++n) {
            int c = colbase + n * 16 + cl;
            bh[n] = *(const half8*)&wthi[(size_t)c * DD + kt * 32 + gq * 8];
            bl[n] = *(const half8*)&wtlo[(size_t)c * DD + kt * 32 + gq * 8];
        }
        #pragma unroll
        for (int m = 0; m < 4; ++m) {
            int row = m * 16 + cl;
            ah[m] = *(const half8*)&Ahi[row * LP2 + kt * 32 + gq * 8];
            al[m] = *(const half8*)&Alo[row * LP2 + kt * 32 + gq * 8];
        }
        #pragma unroll
        for (int m = 0; m < 4; ++m)
            #pragma unroll
            for (int n = 0; n < 2; ++n) {
                acc[m][n]  = __builtin_amdgcn_mfma_f32_16x16x32_f16(ah[m], bh[n], acc[m][n], 0, 0, 0);
                acc2[m][n] = __builtin_amdgcn_mfma_f32_16x16x32_f16(ah[m], bl[n], acc2[m][n], 0, 0, 0);
                acc2[m][n] = __builtin_amdgcn_mfma_f32_16x16x32_f16(al[m], bh[n], acc2[m][n], 0, 0, 0);
            }
    }

    float bv[2], gv[2], bev[2];
    #pragma unroll
    for (int n = 0; n < 2; ++n) {
        int c = colbase + n * 16 + cl;
        bv[n] = bias[c]; gv[n] = gamma[c]; bev[n] = beta[c];
    }
    #pragma unroll
    for (int m = 0; m < 4; ++m)
        #pragma unroll
        for (int j = 0; j < 4; ++j) {
            float s1 = 0.f, s2 = 0.f;
            #pragma unroll
            for (int n = 0; n < 2; ++n) {
                float z = acc[m][n][j] + acc2[m][n][j] * (1.0f / 2048.0f) + bv[n];
                acc[m][n][j] = z;
                s1 += z; s2 += z * z;
            }
            #pragma unroll
            for (int msk = 1; msk <= 8; msk <<= 1) {
                s1 += __shfl_xor(s1, msk);
                s2 += __shfl_xor(s2, msk);
            }
            if (cl == 0) part[wc][m * 16 + gq * 4 + j] = make_float2(s1, s2);
        }
    __syncthreads();
    #pragma unroll
    for (int m = 0; m < 4; ++m)
        #pragma unroll
        for (int j = 0; j < 4; ++j) {
            int r = m * 16 + gq * 4 + j;
            float2 p0 = part[0][r], p1 = part[1][r], p2 = part[2][r], p3 = part[3][r];
            float s1 = p0.x + p1.x + p2.x + p3.x;
            float s2 = p0.y + p1.y + p2.y + p3.y;
            float mean = s1 * (1.0f / DD);
            float inv = rsqrtf(s2 * (1.0f / DD) - mean * mean + LNEPS);
            int grow = rb + r;
            if (grow < nrows) {
                #pragma unroll
                for (int n = 0; n < 2; ++n) {
                    float o = fmaxf((acc[m][n][j] - mean) * inv * gv[n] + bev[n], 0.f);
                    int c = colbase + n * 16 + cl;
                    if (mode == 0) {
                        _Float16 oh = (_Float16)o;
                        _Float16 ol = (_Float16)((o - (float)oh) * 2048.0f);
                        yhi[(size_t)grow * DD + c] = oh;
                        ylo[(size_t)grow * DD + c] = ol;
                    } else {
                        yf[(size_t)grow * DD + c] = o;
                    }
                }
            }
        }
}

// ---------------- pooling ----------------
__global__ __launch_bounds__(256) void zero_int_k(int* __restrict__ p, int n) {
    int i = blockIdx.x * 256 + threadIdx.x;
    if (i < n) p[i] = 0;
}

__global__ __launch_bounds__(256) void pool_k(const float* __restrict__ h,
                                              const int* __restrict__ gid,
                                              float* __restrict__ hg) {
    const int c = threadIdx.x & 127;
    const int half = threadIdx.x >> 7;
    int base = blockIdx.x * 128 + half * 64;
    if (base >= NN) return;
    int end = base + 64; if (end > NN) end = NN;
    float acc = 0.f;
    int cg = gid[base];
    for (int n = base; n < end; ++n) {
        int g = gid[n];
        if (g != cg) {
            unsafeAtomicAdd(&hg[cg * DD + c], acc);
            acc = 0.f; cg = g;
        }
        acc += h[(size_t)n * DD + c];
    }
    unsafeAtomicAdd(&hg[cg * DD + c], acc);
}

// ---------------- head MLP ----------------
__global__ __launch_bounds__(128) void head2_k(const float* __restrict__ hg,
                                               const float* __restrict__ desc,
                                               const float* __restrict__ fc1W,
                                               const float* __restrict__ fc1b,
                                               const float* __restrict__ n1g,
                                               const float* __restrict__ n1b,
                                               const float* __restrict__ fc2W,
                                               const float* __restrict__ fc2b,
                                               float* __restrict__ out) {
    const int g = blockIdx.x;
    const int c = threadIdx.x;
    __shared__ float cat[DD + XX];
    __shared__ float red[4];
    cat[c] = hg[g * DD + c];
    if (c < XX) cat[DD + c] = desc[g * XX + c];
    __syncthreads();
    float z = fc1b[c];
    for (int k = 0; k < DD + XX; ++k) z += cat[k] * fc1W[k * DD + c];
    float s1 = z, s2 = z * z;
    #pragma unroll
    for (int m = 1; m <= 32; m <<= 1) { s1 += __shfl_xor(s1, m); s2 += __shfl_xor(s2, m); }
    int wid = c >> 6, lane = c & 63;
    if (lane == 0) { red[wid] = s1; red[2 + wid] = s2; }
    __syncthreads();
    s1 = red[0] + red[1]; s2 = red[2] + red[3];
    float mean = s1 * (1.0f / DD);
    float var  = s2 * (1.0f / DD) - mean * mean;
    float inv  = rsqrtf(var + LNEPS);
    float zr = fmaxf((z - mean) * inv * n1g[c] + n1b[c], 0.f);
    float p = zr * fc2W[c];
    #pragma unroll
    for (int m = 1; m <= 32; m <<= 1) p += __shfl_xor(p, m);
    __syncthreads();
    if (lane == 0) red[wid] = p;
    __syncthreads();
    if (c == 0) out[g] = red[0] + red[1] + fc2b[0];
}

extern "C" void kernel_launch(void* const* d_in, const int* in_sizes, int n_in,
                              void* d_out, int out_size, void* d_ws, size_t ws_size,
                              hipStream_t stream) {
    const float* h    = (const float*)d_in[0];
    const float* desc = (const float*)d_in[1];
    const int*   src  = (const int*)d_in[2];
    const int*   dst  = (const int*)d_in[3];
    const int*   gid  = (const int*)d_in[4];
    const float* W1   = (const float*)d_in[5];
    const float* b1   = (const float*)d_in[6];
    const float* g1   = (const float*)d_in[7];
    const float* be1  = (const float*)d_in[8];
    const float* W2   = (const float*)d_in[9];
    const float* b2   = (const float*)d_in[10];
    const float* eps  = (const float*)d_in[11];
    const float* ng   = (const float*)d_in[12];
    const float* nb   = (const float*)d_in[13];
    const float* fc1W = (const float*)d_in[14];
    const float* fc1b = (const float*)d_in[15];
    const float* n1g  = (const float*)d_in[16];
    const float* n1b  = (const float*)d_in[17];
    const float* fc2W = (const float*)d_in[18];
    const float* fc2b = (const float*)d_in[19];
    float* out = (float*)d_out;

    float* nx = (float*)d_ws;                         // NN*DD f32
    _Float16* XAhi = (_Float16*)(nx + (size_t)NN * DD);
    _Float16* XAlo = XAhi + (size_t)NN * DD;
    float* hg = (float*)(XAlo + (size_t)NN * DD);     // NG*DD
    int* row_ptr = (int*)(hg + (size_t)NG * DD);
    int* col     = row_ptr + NN + 4;
    int* btot    = col + NE;
    _Float16* wt = (_Float16*)(((uintptr_t)(btot + 512) + 255) & ~(uintptr_t)255);
    // overlays (dead before layer-0 agg writes XAhi/XAlo):
    int2* pairs = (int2*)XAhi;    // NE*8B = 12.8MB <= 25.6MB
    int*  hist  = (int*)XAlo;     // NBK*256*4B = 400KB

    wprep_k<<<(6 * 16384 + 255) / 256, 256, 0, stream>>>(W1, W2, wt);

    // ---- bucket-sorted CSR build ----
    hist_k<<<256, 256, 0, stream>>>(dst, hist);
    bucketpref_k<<<NBK, 256, 0, stream>>>(hist, btot);
    scan_bsums2_k<<<1, 512, 0, stream>>>(btot, NBK, row_ptr);
    scatter_pairs_k<<<256, 256, 0, stream>>>(src, dst, btot, hist, pairs);
    bucket_csr_k<<<NBK, 256, 0, stream>>>(pairs, btot, row_ptr, col);

    const int gemm_grid = (NN + 63) / 64;   // 1563
    const float* cur = h;
    for (int l = 0; l < NL; ++l) {
        const _Float16* w1hi = wt + (size_t)(l * 2 + 0) * 2 * 16384;
        const _Float16* w1lo = w1hi + 16384;
        const _Float16* w2hi = wt + (size_t)(l * 2 + 1) * 2 * 16384;
        const _Float16* w2lo = w2hi + 16384;
        agg_k<<<(NN + 7) / 8, 256, 0, stream>>>(cur, row_ptr, col, XAhi, XAlo, eps, l);
        gemm_mfma_k<<<gemm_grid, 256, 0, stream>>>(
            XAhi, XAlo, w1hi, w1lo, b1 + l * DD, g1 + l * DD, be1 + l * DD,
            XAhi, XAlo, nullptr, 0, NN);
        gemm_mfma_k<<<gemm_grid, 256, 0, stream>>>(
            XAhi, XAlo, w2hi, w2lo, b2 + l * DD, ng + l * DD, nb + l * DD,
            nullptr, nullptr, nx, 1, NN);
        cur = nx;
    }
    zero_int_k<<<(NG * DD + 255) / 256, 256, 0, stream>>>((int*)hg, NG * DD);
    pool_k<<<(NN + 127) / 128, 256, 0, stream>>>(cur, gid, hg);
    head2_k<<<NG, 128, 0, stream>>>(hg, desc, fc1W, fc1b, n1g, n1b, fc2W, fc2b, out);
}

// Round 6
// 714.567 us; speedup vs baseline: 12.1988x; 1.1794x over previous
//
#include <hip/hip_runtime.h>

#define NN 100000
#define NE 1600000
#define DD 128
#define NG 256
#define XX 16
#define NL 3
#define NBK 391          // buckets of 256 dst each
#define LNEPS 1e-5f

typedef _Float16 half8 __attribute__((ext_vector_type(8)));
typedef _Float16 half4v __attribute__((ext_vector_type(4)));
typedef float f32x4 __attribute__((ext_vector_type(4)));

// ---------------- bucket-sorted CSR build ----------------
__global__ __launch_bounds__(256) void hist_k(const int* __restrict__ dst,
                                              int* __restrict__ hist) {
    __shared__ int lh[NBK];
    const int t = threadIdx.x, blk = blockIdx.x;
    for (int i = t; i < NBK; i += 256) lh[i] = 0;
    __syncthreads();
    const int base = blk * (NE / 256);
    for (int e = base + t; e < base + NE / 256; e += 256)
        atomicAdd(&lh[dst[e] >> 8], 1);
    __syncthreads();
    for (int i = t; i < NBK; i += 256) hist[i * 256 + blk] = lh[i];
}

__global__ __launch_bounds__(256) void bucketpref_k(int* __restrict__ hist,
                                                    int* __restrict__ btot) {
    __shared__ int sd[256];
    const int b = blockIdx.x, t = threadIdx.x;
    int v = hist[b * 256 + t];
    sd[t] = v;
    __syncthreads();
    #pragma unroll
    for (int off = 1; off < 256; off <<= 1) {
        int x = t >= off ? sd[t - off] : 0;
        __syncthreads();
        sd[t] += x;
        __syncthreads();
    }
    hist[b * 256 + t] = sd[t] - v;
    if (t == 255) btot[b] = sd[255];
}

__global__ __launch_bounds__(512) void scan_bsums2_k(int* __restrict__ bsum, int nb,
                                                     int* __restrict__ row_ptr) {
    __shared__ int sd[512];
    int t = threadIdx.x;
    int v = t < nb ? bsum[t] : 0;
    sd[t] = v;
    __syncthreads();
    #pragma unroll
    for (int off = 1; off < 512; off <<= 1) {
        int x = t >= off ? sd[t - off] : 0;
        __syncthreads();
        sd[t] += x;
        __syncthreads();
    }
    if (t < nb) bsum[t] = sd[t] - v;
    if (t == 0) row_ptr[NN] = NE;
}

// packed pair: (dst&255)<<17 | src   (src < 2^17)
__global__ __launch_bounds__(256) void scatter_pairs_k(const int* __restrict__ src,
                                                       const int* __restrict__ dst,
                                                       const int* __restrict__ btot,
                                                       const int* __restrict__ hist,
                                                       unsigned* __restrict__ pairs) {
    __shared__ int off[NBK];
    const int t = threadIdx.x, blk = blockIdx.x;
    for (int i = t; i < NBK; i += 256)
        off[i] = btot[i] + hist[i * 256 + blk];
    __syncthreads();
    const int base = blk * (NE / 256);
    for (int e = base + t; e < base + NE / 256; e += 256) {
        int d = dst[e];
        int pos = atomicAdd(&off[d >> 8], 1);
        pairs[pos] = ((unsigned)(d & 255) << 17) | (unsigned)src[e];
    }
}

__global__ __launch_bounds__(256) void bucket_csr_k(const unsigned* __restrict__ pairs,
                                                    const int* __restrict__ btot,
                                                    int* __restrict__ row_ptr,
                                                    int* __restrict__ col) {
    __shared__ int cntL[256], ex[256], rnk[256], sd[256];
    const int b = blockIdx.x, t = threadIdx.x;
    const int nbase = b << 8;
    const int ps = btot[b];
    const int pe = (b == NBK - 1) ? NE : btot[b + 1];
    cntL[t] = 0; rnk[t] = 0;
    __syncthreads();
    for (int i = ps + t; i < pe; i += 256)
        atomicAdd(&cntL[pairs[i] >> 17], 1);
    __syncthreads();
    int v = cntL[t];
    sd[t] = v;
    __syncthreads();
    #pragma unroll
    for (int off = 1; off < 256; off <<= 1) {
        int x = t >= off ? sd[t - off] : 0;
        __syncthreads();
        sd[t] += x;
        __syncthreads();
    }
    ex[t] = sd[t] - v;
    int node = nbase + t;
    if (node < NN) row_ptr[node] = ps + ex[t];
    __syncthreads();
    for (int i = ps + t; i < pe; i += 256) {
        unsigned p = pairs[i];
        int li = p >> 17;
        int r = atomicAdd(&rnk[li], 1);
        col[ps + ex[li] + r] = (int)(p & 0x1FFFFu);
    }
}

// ---------------- layer-0 f16 gather copy ----------------
__global__ __launch_bounds__(256) void h16init_k(const float* __restrict__ h,
                                                 _Float16* __restrict__ h16) {
    size_t i = (size_t)blockIdx.x * 256 + threadIdx.x;
    if (i >= (size_t)NN * DD / 4) return;
    float4 v = ((const float4*)h)[i];
    half4v o;
    o.x = (_Float16)v.x; o.y = (_Float16)v.y; o.z = (_Float16)v.z; o.w = (_Float16)v.w;
    ((half4v*)h16)[i] = o;
}

// ---------------- aggregation: split_f16( (1+eps)*h_f32[v] + sum f16(h[u]) ) ----------------
__global__ __launch_bounds__(256) void agg_k(const float* __restrict__ h,
                                             const _Float16* __restrict__ h16,
                                             const int* __restrict__ row_ptr,
                                             const int* __restrict__ col,
                                             _Float16* __restrict__ xhi,
                                             _Float16* __restrict__ xlo,
                                             const float* __restrict__ eps, int l) {
    const float e = 1.0f + eps[l];
    const int v = blockIdx.x * 8 + (threadIdx.x >> 5);
    const int q = threadIdx.x & 31;
    if (v >= NN) return;
    const int lo = row_ptr[v], hi = row_ptr[v + 1];
    float4 a0 = *(const float4*)&h[(size_t)v * DD + q * 4];
    a0.x *= e; a0.y *= e; a0.z *= e; a0.w *= e;
    float4 a1 = make_float4(0.f, 0.f, 0.f, 0.f);
    float4 a2 = make_float4(0.f, 0.f, 0.f, 0.f);
    float4 a3 = make_float4(0.f, 0.f, 0.f, 0.f);
    int i = lo;
    for (; i + 8 <= hi; i += 8) {
        int s0 = col[i],     s1 = col[i + 1], s2 = col[i + 2], s3 = col[i + 3];
        int s4 = col[i + 4], s5 = col[i + 5], s6 = col[i + 6], s7 = col[i + 7];
        half4v g0 = *(const half4v*)&h16[(size_t)s0 * DD + q * 4];
        half4v g1 = *(const half4v*)&h16[(size_t)s1 * DD + q * 4];
        half4v g2 = *(const half4v*)&h16[(size_t)s2 * DD + q * 4];
        half4v g3 = *(const half4v*)&h16[(size_t)s3 * DD + q * 4];
        half4v g4 = *(const half4v*)&h16[(size_t)s4 * DD + q * 4];
        half4v g5 = *(const half4v*)&h16[(size_t)s5 * DD + q * 4];
        half4v g6 = *(const half4v*)&h16[(size_t)s6 * DD + q * 4];
        half4v g7 = *(const half4v*)&h16[(size_t)s7 * DD + q * 4];
        a0.x += (float)g0.x + (float)g4.x; a0.y += (float)g0.y + (float)g4.y;
        a0.z += (float)g0.z + (float)g4.z; a0.w += (float)g0.w + (float)g4.w;
        a1.x += (float)g1.x + (float)g5.x; a1.y += (float)g1.y + (float)g5.y;
        a1.z += (float)g1.z + (float)g5.z; a1.w += (float)g1.w + (float)g5.w;
        a2.x += (float)g2.x + (float)g6.x; a2.y += (float)g2.y + (float)g6.y;
        a2.z += (float)g2.z + (float)g6.z; a2.w += (float)g2.w + (float)g6.w;
        a3.x += (float)g3.x + (float)g7.x; a3.y += (float)g3.y + (float)g7.y;
        a3.z += (float)g3.z + (float)g7.z; a3.w += (float)g3.w + (float)g7.w;
    }
    for (; i + 2 <= hi; i += 2) {
        int s0 = col[i], s1 = col[i + 1];
        half4v g0 = *(const half4v*)&h16[(size_t)s0 * DD + q * 4];
        half4v g1 = *(const half4v*)&h16[(size_t)s1 * DD + q * 4];
        a0.x += (float)g0.x; a0.y += (float)g0.y; a0.z += (float)g0.z; a0.w += (float)g0.w;
        a1.x += (float)g1.x; a1.y += (float)g1.y; a1.z += (float)g1.z; a1.w += (float)g1.w;
    }
    if (i < hi) {
        int s = col[i];
        half4v g = *(const half4v*)&h16[(size_t)s * DD + q * 4];
        a0.x += (float)g.x; a0.y += (float)g.y; a0.z += (float)g.z; a0.w += (float)g.w;
    }
    a0.x += a1.x + a2.x + a3.x;
    a0.y += a1.y + a2.y + a3.y;
    a0.z += a1.z + a2.z + a3.z;
    a0.w += a1.w + a2.w + a3.w;
    union { _Float16 hh[4]; float2 f; } ph, pl;
    ph.hh[0] = (_Float16)a0.x; pl.hh[0] = (_Float16)((a0.x - (float)ph.hh[0]) * 2048.0f);
    ph.hh[1] = (_Float16)a0.y; pl.hh[1] = (_Float16)((a0.y - (float)ph.hh[1]) * 2048.0f);
    ph.hh[2] = (_Float16)a0.z; pl.hh[2] = (_Float16)((a0.z - (float)ph.hh[2]) * 2048.0f);
    ph.hh[3] = (_Float16)a0.w; pl.hh[3] = (_Float16)((a0.w - (float)ph.hh[3]) * 2048.0f);
    *(float2*)&xhi[(size_t)v * DD + q * 4] = ph.f;
    *(float2*)&xlo[(size_t)v * DD + q * 4] = pl.f;
}

// ---------------- W split+transpose prep ----------------
__global__ __launch_bounds__(256) void wprep_k(const float* __restrict__ W1,
                                               const float* __restrict__ W2,
                                               _Float16* __restrict__ wt) {
    int idx = blockIdx.x * 256 + threadIdx.x;
    if (idx >= 6 * 16384) return;
    int mtx = idx >> 14;
    int r = idx & 16383;                            // col*128 + k
    int c = r >> 7, k = r & 127;
    int l = mtx >> 1;
    const float* W = (mtx & 1) ? W2 : W1;
    float w = W[(size_t)l * 16384 + k * 128 + c];
    _Float16 hi = (_Float16)w;
    _Float16 lo = (_Float16)((w - (float)hi) * 2048.0f);
    wt[(size_t)mtx * 2 * 16384 + r] = hi;
    wt[(size_t)mtx * 2 * 16384 + 16384 + r] = lo;
}

// ---------------- MFMA GEMM: y = relu(LN(x @ W + b)) ----------------
// mode 0: write split f16 (yhi/ylo). mode 1: write f32 yf (+ optional f16 y16 copy)
#define LP2 136
__global__ __launch_bounds__(256) void gemm_mfma_k(const _Float16* __restrict__ xhi,
                                                   const _Float16* __restrict__ xlo,
                                                   const _Float16* __restrict__ wthi,
                                                   const _Float16* __restrict__ wtlo,
                                                   const float* __restrict__ bias,
                                                   const float* __restrict__ gamma,
                                                   const float* __restrict__ beta,
                                                   _Float16* __restrict__ yhi,
                                                   _Float16* __restrict__ ylo,
                                                   float* __restrict__ yf,
                                                   _Float16* __restrict__ y16,
                                                   int mode, int nrows) {
    __shared__ _Float16 Ahi[64 * LP2];
    __shared__ _Float16 Alo[64 * LP2];
    __shared__ float2 part[4][64];

    const int tid = threadIdx.x;
    const int wc = tid >> 6;
    const int lane = tid & 63;
    const int cl = lane & 15, gq = lane >> 4;
    const int rb = blockIdx.x * 64;
    const int colbase = wc * 32;

    f32x4 acc[4][2] = {};
    f32x4 acc2[4][2] = {};

    #pragma unroll
    for (int i = 0; i < 4; ++i) {
        int c = tid + 256 * i;
        int row = c >> 4, kc = c & 15;
        int gr = rb + row;
        int sr = gr < nrows ? gr : 0;
        *(float4*)&Ahi[row * LP2 + kc * 8] =
            *(const float4*)&xhi[(size_t)sr * DD + kc * 8];
        *(float4*)&Alo[row * LP2 + kc * 8] =
            *(const float4*)&xlo[(size_t)sr * DD + kc * 8];
    }
    __syncthreads();

    #pragma unroll
    for (int kt = 0; kt < 4; ++kt) {
        half8 bh[2], bl[2], ah[4], al[4];
        #pragma unroll
        for (int n = 0; n < 2; ++n) {
            int c = colbase + n * 16 + cl;
            bh[n] = *(const half8*)&wthi[(size_t)c * DD + kt * 32 + gq * 8];
            bl[n] = *(const half8*)&wtlo[(size_t)c * DD + kt * 32 + gq * 8];
        }
        #pragma unroll
        for (int m = 0; m < 4; ++m) {
            int row = m * 16 + cl;
            ah[m] = *(const half8*)&Ahi[row * LP2 + kt * 32 + gq * 8];
            al[m] = *(const half8*)&Alo[row * LP2 + kt * 32 + gq * 8];
        }
        #pragma unroll
        for (int m = 0; m < 4; ++m)
            #pragma unroll
            for (int n = 0; n < 2; ++n) {
                acc[m][n]  = __builtin_amdgcn_mfma_f32_16x16x32_f16(ah[m], bh[n], acc[m][n], 0, 0, 0);
                acc2[m][n] = __builtin_amdgcn_mfma_f32_16x16x32_f16(ah[m], bl[n], acc2[m][n], 0, 0, 0);
                acc2[m][n] = __builtin_amdgcn_mfma_f32_16x16x32_f16(al[m], bh[n], acc2[m][n], 0, 0, 0);
            }
    }

    float bv[2], gv[2], bev[2];
    #pragma unroll
    for (int n = 0; n < 2; ++n) {
        int c = colbase + n * 16 + cl;
        bv[n] = bias[c]; gv[n] = gamma[c]; bev[n] = beta[c];
    }
    #pragma unroll
    for (int m = 0; m < 4; ++m)
        #pragma unroll
        for (int j = 0; j < 4; ++j) {
            float s1 = 0.f, s2 = 0.f;
            #pragma unroll
            for (int n = 0; n < 2; ++n) {
                float z = acc[m][n][j] + acc2[m][n][j] * (1.0f / 2048.0f) + bv[n];
                acc[m][n][j] = z;
                s1 += z; s2 += z * z;
            }
            #pragma unroll
            for (int msk = 1; msk <= 8; msk <<= 1) {
                s1 += __shfl_xor(s1, msk);
                s2 += __shfl_xor(s2, msk);
            }
            if (cl == 0) part[wc][m * 16 + gq * 4 + j] = make_float2(s1, s2);
        }
    __syncthreads();
    #pragma unroll
    for (int m = 0; m < 4; ++m)
        #pragma unroll
        for (int j = 0; j < 4; ++j) {
            int r = m * 16 + gq * 4 + j;
            float2 p0 = part[0][r], p1 = part[1][r], p2 = part[2][r], p3 = part[3][r];
            float s1 = p0.x + p1.x + p2.x + p3.x;
            float s2 = p0.y + p1.y + p2.y + p3.y;
            float mean = s1 * (1.0f / DD);
            float inv = rsqrtf(s2 * (1.0f / DD) - mean * mean + LNEPS);
            int grow = rb + r;
            if (grow < nrows) {
                #pragma unroll
                for (int n = 0; n < 2; ++n) {
                    float o = fmaxf((acc[m][n][j] - mean) * inv * gv[n] + bev[n], 0.f);
                    int c = colbase + n * 16 + cl;
                    if (mode == 0) {
                        _Float16 oh = (_Float16)o;
                        _Float16 ol = (_Float16)((o - (float)oh) * 2048.0f);
                        yhi[(size_t)grow * DD + c] = oh;
                        ylo[(size_t)grow * DD + c] = ol;
                    } else {
                        yf[(size_t)grow * DD + c] = o;
                        if (y16) y16[(size_t)grow * DD + c] = (_Float16)o;
                    }
                }
            }
        }
}

// ---------------- pooling ----------------
__global__ __launch_bounds__(256) void zero_int_k(int* __restrict__ p, int n) {
    int i = blockIdx.x * 256 + threadIdx.x;
    if (i < n) p[i] = 0;
}

__global__ __launch_bounds__(256) void pool_k(const float* __restrict__ h,
                                              const int* __restrict__ gid,
                                              float* __restrict__ hg) {
    const int c = threadIdx.x & 127;
    const int half = threadIdx.x >> 7;
    int base = blockIdx.x * 128 + half * 64;
    if (base >= NN) return;
    int end = base + 64; if (end > NN) end = NN;
    float acc = 0.f;
    int cg = gid[base];
    for (int n = base; n < end; ++n) {
        int g = gid[n];
        if (g != cg) {
            unsafeAtomicAdd(&hg[cg * DD + c], acc);
            acc = 0.f; cg = g;
        }
        acc += h[(size_t)n * DD + c];
    }
    unsafeAtomicAdd(&hg[cg * DD + c], acc);
}

// ---------------- head MLP ----------------
__global__ __launch_bounds__(128) void head2_k(const float* __restrict__ hg,
                                               const float* __restrict__ desc,
                                               const float* __restrict__ fc1W,
                                               const float* __restrict__ fc1b,
                                               const float* __restrict__ n1g,
                                               const float* __restrict__ n1b,
                                               const float* __restrict__ fc2W,
                                               const float* __restrict__ fc2b,
                                               float* __restrict__ out) {
    const int g = blockIdx.x;
    const int c = threadIdx.x;
    __shared__ float cat[DD + XX];
    __shared__ float red[4];
    cat[c] = hg[g * DD + c];
    if (c < XX) cat[DD + c] = desc[g * XX + c];
    __syncthreads();
    float z = fc1b[c];
    for (int k = 0; k < DD + XX; ++k) z += cat[k] * fc1W[k * DD + c];
    float s1 = z, s2 = z * z;
    #pragma unroll
    for (int m = 1; m <= 32; m <<= 1) { s1 += __shfl_xor(s1, m); s2 += __shfl_xor(s2, m); }
    int wid = c >> 6, lane = c & 63;
    if (lane == 0) { red[wid] = s1; red[2 + wid] = s2; }
    __syncthreads();
    s1 = red[0] + red[1]; s2 = red[2] + red[3];
    float mean = s1 * (1.0f / DD);
    float var  = s2 * (1.0f / DD) - mean * mean;
    float inv  = rsqrtf(var + LNEPS);
    float zr = fmaxf((z - mean) * inv * n1g[c] + n1b[c], 0.f);
    float p = zr * fc2W[c];
    #pragma unroll
    for (int m = 1; m <= 32; m <<= 1) p += __shfl_xor(p, m);
    __syncthreads();
    if (lane == 0) red[wid] = p;
    __syncthreads();
    if (c == 0) out[g] = red[0] + red[1] + fc2b[0];
}

extern "C" void kernel_launch(void* const* d_in, const int* in_sizes, int n_in,
                              void* d_out, int out_size, void* d_ws, size_t ws_size,
                              hipStream_t stream) {
    const float* h    = (const float*)d_in[0];
    const float* desc = (const float*)d_in[1];
    const int*   src  = (const int*)d_in[2];
    const int*   dst  = (const int*)d_in[3];
    const int*   gid  = (const int*)d_in[4];
    const float* W1   = (const float*)d_in[5];
    const float* b1   = (const float*)d_in[6];
    const float* g1   = (const float*)d_in[7];
    const float* be1  = (const float*)d_in[8];
    const float* W2   = (const float*)d_in[9];
    const float* b2   = (const float*)d_in[10];
    const float* eps  = (const float*)d_in[11];
    const float* ng   = (const float*)d_in[12];
    const float* nb   = (const float*)d_in[13];
    const float* fc1W = (const float*)d_in[14];
    const float* fc1b = (const float*)d_in[15];
    const float* n1g  = (const float*)d_in[16];
    const float* n1b  = (const float*)d_in[17];
    const float* fc2W = (const float*)d_in[18];
    const float* fc2b = (const float*)d_in[19];
    float* out = (float*)d_out;

    float* nx = (float*)d_ws;                         // NN*DD f32
    _Float16* XAhi = (_Float16*)(nx + (size_t)NN * DD);
    _Float16* XAlo = XAhi + (size_t)NN * DD;
    _Float16* h16  = XAlo + (size_t)NN * DD;          // f16 gather copy
    float* hg = (float*)(h16 + (size_t)NN * DD);      // NG*DD
    int* row_ptr = (int*)(hg + (size_t)NG * DD);
    int* col     = row_ptr + NN + 4;
    int* btot    = col + NE;
    _Float16* wt = (_Float16*)(((uintptr_t)(btot + 512) + 255) & ~(uintptr_t)255);
    // overlays (dead before layer-0 agg writes XAhi/XAlo):
    unsigned* pairs = (unsigned*)XAhi;   // NE*4B = 6.4MB
    int*      hist  = (int*)XAlo;        // NBK*256*4B = 400KB

    wprep_k<<<(6 * 16384 + 255) / 256, 256, 0, stream>>>(W1, W2, wt);
    h16init_k<<<(NN * DD / 4 + 255) / 256, 256, 0, stream>>>(h, h16);

    hist_k<<<256, 256, 0, stream>>>(dst, hist);
    bucketpref_k<<<NBK, 256, 0, stream>>>(hist, btot);
    scan_bsums2_k<<<1, 512, 0, stream>>>(btot, NBK, row_ptr);
    scatter_pairs_k<<<256, 256, 0, stream>>>(src, dst, btot, hist, pairs);
    bucket_csr_k<<<NBK, 256, 0, stream>>>(pairs, btot, row_ptr, col);

    const int gemm_grid = (NN + 63) / 64;   // 1563
    const float* cur = h;
    for (int l = 0; l < NL; ++l) {
        const _Float16* w1hi = wt + (size_t)(l * 2 + 0) * 2 * 16384;
        const _Float16* w1lo = w1hi + 16384;
        const _Float16* w2hi = wt + (size_t)(l * 2 + 1) * 2 * 16384;
        const _Float16* w2lo = w2hi + 16384;
        agg_k<<<(NN + 7) / 8, 256, 0, stream>>>(cur, h16, row_ptr, col, XAhi, XAlo, eps, l);
        gemm_mfma_k<<<gemm_grid, 256, 0, stream>>>(
            XAhi, XAlo, w1hi, w1lo, b1 + l * DD, g1 + l * DD, be1 + l * DD,
            XAhi, XAlo, nullptr, nullptr, 0, NN);
        gemm_mfma_k<<<gemm_grid, 256, 0, stream>>>(
            XAhi, XAlo, w2hi, w2lo, b2 + l * DD, ng + l * DD, nb + l * DD,
            nullptr, nullptr, nx, (l < NL - 1) ? h16 : nullptr, 1, NN);
        cur = nx;
    }
    zero_int_k<<<(NG * DD + 255) / 256, 256, 0, stream>>>((int*)hg, NG * DD);
    pool_k<<<(NN + 127) / 128, 256, 0, stream>>>(cur, gid, hg);
    head2_k<<<NG, 128, 0, stream>>>(hg, desc, fc1W, fc1b, n1g, n1b, fc2W, fc2b, out);
}

// Round 7
// 615.348 us; speedup vs baseline: 14.1658x; 1.1612x over previous
//
#include <hip/hip_runtime.h>

#define NN 100000
#define NE 1600000
#define DD 128
#define NG 256
#define XX 16
#define NL 3
#define NBK 391          // buckets of 256 dst each
#define LNEPS 1e-5f

typedef _Float16 half8 __attribute__((ext_vector_type(8)));
typedef _Float16 half4v __attribute__((ext_vector_type(4)));
typedef float f32x4 __attribute__((ext_vector_type(4)));

// ---------------- bucket-sorted CSR build ----------------
__global__ __launch_bounds__(256) void hist_k(const int* __restrict__ dst,
                                              int* __restrict__ hist) {
    __shared__ int lh[NBK];
    const int t = threadIdx.x, blk = blockIdx.x;
    for (int i = t; i < NBK; i += 256) lh[i] = 0;
    __syncthreads();
    const int base = blk * (NE / 256);
    for (int e = base + t; e < base + NE / 256; e += 256)
        atomicAdd(&lh[dst[e] >> 8], 1);
    __syncthreads();
    for (int i = t; i < NBK; i += 256) hist[i * 256 + blk] = lh[i];
}

__global__ __launch_bounds__(256) void bucketpref_k(int* __restrict__ hist,
                                                    int* __restrict__ btot) {
    __shared__ int sd[256];
    const int b = blockIdx.x, t = threadIdx.x;
    int v = hist[b * 256 + t];
    sd[t] = v;
    __syncthreads();
    #pragma unroll
    for (int off = 1; off < 256; off <<= 1) {
        int x = t >= off ? sd[t - off] : 0;
        __syncthreads();
        sd[t] += x;
        __syncthreads();
    }
    hist[b * 256 + t] = sd[t] - v;
    if (t == 255) btot[b] = sd[255];
}

__global__ __launch_bounds__(512) void scan_bsums2_k(int* __restrict__ bsum, int nb,
                                                     int* __restrict__ row_ptr) {
    __shared__ int sd[512];
    int t = threadIdx.x;
    int v = t < nb ? bsum[t] : 0;
    sd[t] = v;
    __syncthreads();
    #pragma unroll
    for (int off = 1; off < 512; off <<= 1) {
        int x = t >= off ? sd[t - off] : 0;
        __syncthreads();
        sd[t] += x;
        __syncthreads();
    }
    if (t < nb) bsum[t] = sd[t] - v;
    if (t == 0) row_ptr[NN] = NE;
}

// packed pair: (dst&255)<<17 | src   (src < 2^17)
__global__ __launch_bounds__(256) void scatter_pairs_k(const int* __restrict__ src,
                                                       const int* __restrict__ dst,
                                                       const int* __restrict__ btot,
                                                       const int* __restrict__ hist,
                                                       unsigned* __restrict__ pairs) {
    __shared__ int off[NBK];
    const int t = threadIdx.x, blk = blockIdx.x;
    for (int i = t; i < NBK; i += 256)
        off[i] = btot[i] + hist[i * 256 + blk];
    __syncthreads();
    const int base = blk * (NE / 256);
    for (int e = base + t; e < base + NE / 256; e += 256) {
        int d = dst[e];
        int pos = atomicAdd(&off[d >> 8], 1);
        pairs[pos] = ((unsigned)(d & 255) << 17) | (unsigned)src[e];
    }
}

__global__ __launch_bounds__(256) void bucket_csr_k(const unsigned* __restrict__ pairs,
                                                    const int* __restrict__ btot,
                                                    int* __restrict__ row_ptr,
                                                    int* __restrict__ col) {
    __shared__ int cntL[256], ex[256], rnk[256], sd[256];
    const int b = blockIdx.x, t = threadIdx.x;
    const int ps = btot[b];
    const int pe = (b == NBK - 1) ? NE : btot[b + 1];
    cntL[t] = 0; rnk[t] = 0;
    __syncthreads();
    for (int i = ps + t; i < pe; i += 256)
        atomicAdd(&cntL[pairs[i] >> 17], 1);
    __syncthreads();
    int v = cntL[t];
    sd[t] = v;
    __syncthreads();
    #pragma unroll
    for (int off = 1; off < 256; off <<= 1) {
        int x = t >= off ? sd[t - off] : 0;
        __syncthreads();
        sd[t] += x;
        __syncthreads();
    }
    ex[t] = sd[t] - v;
    int node = (b << 8) + t;
    if (node < NN) row_ptr[node] = ps + ex[t];
    __syncthreads();
    for (int i = ps + t; i < pe; i += 256) {
        unsigned p = pairs[i];
        int li = p >> 17;
        int r = atomicAdd(&rnk[li], 1);
        col[ps + ex[li] + r] = (int)(p & 0x1FFFFu);
    }
}

// ---------------- layer-0 f16 copy ----------------
__global__ __launch_bounds__(256) void h16init_k(const float* __restrict__ h,
                                                 _Float16* __restrict__ h16) {
    size_t i = (size_t)blockIdx.x * 256 + threadIdx.x;
    if (i >= (size_t)NN * DD / 4) return;
    float4 v = ((const float4*)h)[i];
    half4v o;
    o.x = (_Float16)v.x; o.y = (_Float16)v.y; o.z = (_Float16)v.z; o.w = (_Float16)v.w;
    ((half4v*)h16)[i] = o;
}

// ---------------- aggregation: x16 = f16( (1+eps)*h_f32[v] + sum f16(h[u]) ) ----------------
__global__ __launch_bounds__(256) void agg_k(const float* __restrict__ h,
                                             const _Float16* __restrict__ h16,
                                             const int* __restrict__ row_ptr,
                                             const int* __restrict__ col,
                                             _Float16* __restrict__ x16,
                                             const float* __restrict__ eps, int l) {
    const float e = 1.0f + eps[l];
    const int v = blockIdx.x * 8 + (threadIdx.x >> 5);
    const int q = threadIdx.x & 31;
    if (v >= NN) return;
    const int lo = row_ptr[v], hi = row_ptr[v + 1];
    float4 a0 = *(const float4*)&h[(size_t)v * DD + q * 4];
    a0.x *= e; a0.y *= e; a0.z *= e; a0.w *= e;
    float4 a1 = make_float4(0.f, 0.f, 0.f, 0.f);
    float4 a2 = make_float4(0.f, 0.f, 0.f, 0.f);
    float4 a3 = make_float4(0.f, 0.f, 0.f, 0.f);
    int i = lo;
    for (; i + 8 <= hi; i += 8) {
        int s0 = col[i],     s1 = col[i + 1], s2 = col[i + 2], s3 = col[i + 3];
        int s4 = col[i + 4], s5 = col[i + 5], s6 = col[i + 6], s7 = col[i + 7];
        half4v g0 = *(const half4v*)&h16[(size_t)s0 * DD + q * 4];
        half4v g1 = *(const half4v*)&h16[(size_t)s1 * DD + q * 4];
        half4v g2 = *(const half4v*)&h16[(size_t)s2 * DD + q * 4];
        half4v g3 = *(const half4v*)&h16[(size_t)s3 * DD + q * 4];
        half4v g4 = *(const half4v*)&h16[(size_t)s4 * DD + q * 4];
        half4v g5 = *(const half4v*)&h16[(size_t)s5 * DD + q * 4];
        half4v g6 = *(const half4v*)&h16[(size_t)s6 * DD + q * 4];
        half4v g7 = *(const half4v*)&h16[(size_t)s7 * DD + q * 4];
        a0.x += (float)g0.x + (float)g4.x; a0.y += (float)g0.y + (float)g4.y;
        a0.z += (float)g0.z + (float)g4.z; a0.w += (float)g0.w + (float)g4.w;
        a1.x += (float)g1.x + (float)g5.x; a1.y += (float)g1.y + (float)g5.y;
        a1.z += (float)g1.z + (float)g5.z; a1.w += (float)g1.w + (float)g5.w;
        a2.x += (float)g2.x + (float)g6.x; a2.y += (float)g2.y + (float)g6.y;
        a2.z += (float)g2.z + (float)g6.z; a2.w += (float)g2.w + (float)g6.w;
        a3.x += (float)g3.x + (float)g7.x; a3.y += (float)g3.y + (float)g7.y;
        a3.z += (float)g3.z + (float)g7.z; a3.w += (float)g3.w + (float)g7.w;
    }
    for (; i + 2 <= hi; i += 2) {
        int s0 = col[i], s1 = col[i + 1];
        half4v g0 = *(const half4v*)&h16[(size_t)s0 * DD + q * 4];
        half4v g1 = *(const half4v*)&h16[(size_t)s1 * DD + q * 4];
        a0.x += (float)g0.x; a0.y += (float)g0.y; a0.z += (float)g0.z; a0.w += (float)g0.w;
        a1.x += (float)g1.x; a1.y += (float)g1.y; a1.z += (float)g1.z; a1.w += (float)g1.w;
    }
    if (i < hi) {
        int s = col[i];
        half4v g = *(const half4v*)&h16[(size_t)s * DD + q * 4];
        a0.x += (float)g.x; a0.y += (float)g.y; a0.z += (float)g.z; a0.w += (float)g.w;
    }
    a0.x += a1.x + a2.x + a3.x;
    a0.y += a1.y + a2.y + a3.y;
    a0.z += a1.z + a2.z + a3.z;
    a0.w += a1.w + a2.w + a3.w;
    half4v o;
    o.x = (_Float16)a0.x; o.y = (_Float16)a0.y; o.z = (_Float16)a0.z; o.w = (_Float16)a0.w;
    *(half4v*)&x16[(size_t)v * DD + q * 4] = o;
}

// ---------------- W split+transpose prep ----------------
__global__ __launch_bounds__(256) void wprep_k(const float* __restrict__ W1,
                                               const float* __restrict__ W2,
                                               _Float16* __restrict__ wt) {
    int idx = blockIdx.x * 256 + threadIdx.x;
    if (idx >= 6 * 16384) return;
    int mtx = idx >> 14;
    int r = idx & 16383;                            // col*128 + k
    int c = r >> 7, k = r & 127;
    int l = mtx >> 1;
    const float* W = (mtx & 1) ? W2 : W1;
    float w = W[(size_t)l * 16384 + k * 128 + c];
    _Float16 hi = (_Float16)w;
    _Float16 lo = (_Float16)((w - (float)hi) * 2048.0f);
    wt[(size_t)mtx * 2 * 16384 + r] = hi;
    wt[(size_t)mtx * 2 * 16384 + 16384 + r] = lo;
}

// ---------------- fused MLP: y = relu(LN2(relu(LN1(x@W1+b1))@W2+b2)) ----------------
// block: 64 rows x 128 cols, 4 warps (32-col strips); x f16, W hi/lo split
#define LP2 136
__global__ __launch_bounds__(256) void mlp_k(const _Float16* __restrict__ x16,
                                             const _Float16* __restrict__ w1hi,
                                             const _Float16* __restrict__ w1lo,
                                             const _Float16* __restrict__ w2hi,
                                             const _Float16* __restrict__ w2lo,
                                             const float* __restrict__ b1,
                                             const float* __restrict__ g1,
                                             const float* __restrict__ be1,
                                             const float* __restrict__ b2,
                                             const float* __restrict__ ngv,
                                             const float* __restrict__ nbv,
                                             float* __restrict__ yf,
                                             _Float16* __restrict__ y16,
                                             int nrows) {
    __shared__ _Float16 At[64 * LP2];
    __shared__ float2 part[4][64];

    const int tid = threadIdx.x;
    const int wc = tid >> 6;
    const int lane = tid & 63;
    const int cl = lane & 15, gq = lane >> 4;
    const int rb = blockIdx.x * 64;
    const int colbase = wc * 32;

    // stage x16 tile (64 x 128 f16)
    #pragma unroll
    for (int i = 0; i < 4; ++i) {
        int c = tid + 256 * i;              // 1024 chunks of 8 f16
        int row = c >> 4, kc = c & 15;
        int gr = rb + row;
        int sr = gr < nrows ? gr : 0;
        *(float4*)&At[row * LP2 + kc * 8] =
            *(const float4*)&x16[(size_t)sr * DD + kc * 8];
    }
    __syncthreads();

    f32x4 acc[4][2] = {};
    f32x4 acc2[4][2] = {};

    // ---- GEMM1 ----
    #pragma unroll
    for (int kt = 0; kt < 4; ++kt) {
        half8 bh[2], bl[2], ah[4];
        #pragma unroll
        for (int n = 0; n < 2; ++n) {
            int c = colbase + n * 16 + cl;
            bh[n] = *(const half8*)&w1hi[(size_t)c * DD + kt * 32 + gq * 8];
            bl[n] = *(const half8*)&w1lo[(size_t)c * DD + kt * 32 + gq * 8];
        }
        #pragma unroll
        for (int m = 0; m < 4; ++m)
            ah[m] = *(const half8*)&At[(m * 16 + cl) * LP2 + kt * 32 + gq * 8];
        #pragma unroll
        for (int m = 0; m < 4; ++m)
            #pragma unroll
            for (int n = 0; n < 2; ++n) {
                acc[m][n]  = __builtin_amdgcn_mfma_f32_16x16x32_f16(ah[m], bh[n], acc[m][n], 0, 0, 0);
                acc2[m][n] = __builtin_amdgcn_mfma_f32_16x16x32_f16(ah[m], bl[n], acc2[m][n], 0, 0, 0);
            }
    }

    // ---- epilogue 1: bias + LN + relu -> At (f16) ----
    float bv[2], gv[2], bev[2];
    #pragma unroll
    for (int n = 0; n < 2; ++n) {
        int c = colbase + n * 16 + cl;
        bv[n] = b1[c]; gv[n] = g1[c]; bev[n] = be1[c];
    }
    #pragma unroll
    for (int m = 0; m < 4; ++m)
        #pragma unroll
        for (int j = 0; j < 4; ++j) {
            float s1 = 0.f, s2 = 0.f;
            #pragma unroll
            for (int n = 0; n < 2; ++n) {
                float z = acc[m][n][j] + acc2[m][n][j] * (1.0f / 2048.0f) + bv[n];
                acc[m][n][j] = z;
                s1 += z; s2 += z * z;
            }
            #pragma unroll
            for (int msk = 1; msk <= 8; msk <<= 1) {
                s1 += __shfl_xor(s1, msk);
                s2 += __shfl_xor(s2, msk);
            }
            if (cl == 0) part[wc][m * 16 + gq * 4 + j] = make_float2(s1, s2);
        }
    __syncthreads();
    #pragma unroll
    for (int m = 0; m < 4; ++m)
        #pragma unroll
        for (int j = 0; j < 4; ++j) {
            int r = m * 16 + gq * 4 + j;
            float2 p0 = part[0][r], p1 = part[1][r], p2 = part[2][r], p3 = part[3][r];
            float s1 = p0.x + p1.x + p2.x + p3.x;
            float s2 = p0.y + p1.y + p2.y + p3.y;
            float mean = s1 * (1.0f / DD);
            float inv = rsqrtf(s2 * (1.0f / DD) - mean * mean + LNEPS);
            #pragma unroll
            for (int n = 0; n < 2; ++n) {
                float o = fmaxf((acc[m][n][j] - mean) * inv * gv[n] + bev[n], 0.f);
                At[r * LP2 + colbase + n * 16 + cl] = (_Float16)o;
            }
        }
    __syncthreads();   // At now holds x1 (f16)

    // ---- GEMM2 ----
    #pragma unroll
    for (int m = 0; m < 4; ++m)
        #pragma unroll
        for (int n = 0; n < 2; ++n) {
            acc[m][n]  = f32x4{0.f, 0.f, 0.f, 0.f};
            acc2[m][n] = f32x4{0.f, 0.f, 0.f, 0.f};
        }
    #pragma unroll
    for (int kt = 0; kt < 4; ++kt) {
        half8 bh[2], bl[2], ah[4];
        #pragma unroll
        for (int n = 0; n < 2; ++n) {
            int c = colbase + n * 16 + cl;
            bh[n] = *(const half8*)&w2hi[(size_t)c * DD + kt * 32 + gq * 8];
            bl[n] = *(const half8*)&w2lo[(size_t)c * DD + kt * 32 + gq * 8];
        }
        #pragma unroll
        for (int m = 0; m < 4; ++m)
            ah[m] = *(const half8*)&At[(m * 16 + cl) * LP2 + kt * 32 + gq * 8];
        #pragma unroll
        for (int m = 0; m < 4; ++m)
            #pragma unroll
            for (int n = 0; n < 2; ++n) {
                acc[m][n]  = __builtin_amdgcn_mfma_f32_16x16x32_f16(ah[m], bh[n], acc[m][n], 0, 0, 0);
                acc2[m][n] = __builtin_amdgcn_mfma_f32_16x16x32_f16(ah[m], bl[n], acc2[m][n], 0, 0, 0);
            }
    }

    // ---- epilogue 2: bias + LN + relu -> global ----
    #pragma unroll
    for (int n = 0; n < 2; ++n) {
        int c = colbase + n * 16 + cl;
        bv[n] = b2[c]; gv[n] = ngv[c]; bev[n] = nbv[c];
    }
    #pragma unroll
    for (int m = 0; m < 4; ++m)
        #pragma unroll
        for (int j = 0; j < 4; ++j) {
            float s1 = 0.f, s2 = 0.f;
            #pragma unroll
            for (int n = 0; n < 2; ++n) {
                float z = acc[m][n][j] + acc2[m][n][j] * (1.0f / 2048.0f) + bv[n];
                acc[m][n][j] = z;
                s1 += z; s2 += z * z;
            }
            #pragma unroll
            for (int msk = 1; msk <= 8; msk <<= 1) {
                s1 += __shfl_xor(s1, msk);
                s2 += __shfl_xor(s2, msk);
            }
            if (cl == 0) part[wc][m * 16 + gq * 4 + j] = make_float2(s1, s2);
        }
    __syncthreads();
    #pragma unroll
    for (int m = 0; m < 4; ++m)
        #pragma unroll
        for (int j = 0; j < 4; ++j) {
            int r = m * 16 + gq * 4 + j;
            float2 p0 = part[0][r], p1 = part[1][r], p2 = part[2][r], p3 = part[3][r];
            float s1 = p0.x + p1.x + p2.x + p3.x;
            float s2 = p0.y + p1.y + p2.y + p3.y;
            float mean = s1 * (1.0f / DD);
            float inv = rsqrtf(s2 * (1.0f / DD) - mean * mean + LNEPS);
            int grow = rb + r;
            if (grow < nrows) {
                #pragma unroll
                for (int n = 0; n < 2; ++n) {
                    float o = fmaxf((acc[m][n][j] - mean) * inv * gv[n] + bev[n], 0.f);
                    int c = colbase + n * 16 + cl;
                    yf[(size_t)grow * DD + c] = o;
                    if (y16) y16[(size_t)grow * DD + c] = (_Float16)o;
                }
            }
        }
}

// ---------------- pooling ----------------
__global__ __launch_bounds__(256) void zero_int_k(int* __restrict__ p, int n) {
    int i = blockIdx.x * 256 + threadIdx.x;
    if (i < n) p[i] = 0;
}

__global__ __launch_bounds__(256) void pool_k(const float* __restrict__ h,
                                              const int* __restrict__ gid,
                                              float* __restrict__ hg) {
    const int c = threadIdx.x & 127;
    const int half = threadIdx.x >> 7;
    int base = blockIdx.x * 128 + half * 64;
    if (base >= NN) return;
    int end = base + 64; if (end > NN) end = NN;
    float acc = 0.f;
    int cg = gid[base];
    for (int n = base; n < end; ++n) {
        int g = gid[n];
        if (g != cg) {
            unsafeAtomicAdd(&hg[cg * DD + c], acc);
            acc = 0.f; cg = g;
        }
        acc += h[(size_t)n * DD + c];
    }
    unsafeAtomicAdd(&hg[cg * DD + c], acc);
}

// ---------------- head MLP ----------------
__global__ __launch_bounds__(128) void head2_k(const float* __restrict__ hg,
                                               const float* __restrict__ desc,
                                               const float* __restrict__ fc1W,
                                               const float* __restrict__ fc1b,
                                               const float* __restrict__ n1g,
                                               const float* __restrict__ n1b,
                                               const float* __restrict__ fc2W,
                                               const float* __restrict__ fc2b,
                                               float* __restrict__ out) {
    const int g = blockIdx.x;
    const int c = threadIdx.x;
    __shared__ float cat[DD + XX];
    __shared__ float red[4];
    cat[c] = hg[g * DD + c];
    if (c < XX) cat[DD + c] = desc[g * XX + c];
    __syncthreads();
    float z = fc1b[c];
    for (int k = 0; k < DD + XX; ++k) z += cat[k] * fc1W[k * DD + c];
    float s1 = z, s2 = z * z;
    #pragma unroll
    for (int m = 1; m <= 32; m <<= 1) { s1 += __shfl_xor(s1, m); s2 += __shfl_xor(s2, m); }
    int wid = c >> 6, lane = c & 63;
    if (lane == 0) { red[wid] = s1; red[2 + wid] = s2; }
    __syncthreads();
    s1 = red[0] + red[1]; s2 = red[2] + red[3];
    float mean = s1 * (1.0f / DD);
    float var  = s2 * (1.0f / DD) - mean * mean;
    float inv  = rsqrtf(var + LNEPS);
    float zr = fmaxf((z - mean) * inv * n1g[c] + n1b[c], 0.f);
    float p = zr * fc2W[c];
    #pragma unroll
    for (int m = 1; m <= 32; m <<= 1) p += __shfl_xor(p, m);
    __syncthreads();
    if (lane == 0) red[wid] = p;
    __syncthreads();
    if (c == 0) out[g] = red[0] + red[1] + fc2b[0];
}

extern "C" void kernel_launch(void* const* d_in, const int* in_sizes, int n_in,
                              void* d_out, int out_size, void* d_ws, size_t ws_size,
                              hipStream_t stream) {
    const float* h    = (const float*)d_in[0];
    const float* desc = (const float*)d_in[1];
    const int*   src  = (const int*)d_in[2];
    const int*   dst  = (const int*)d_in[3];
    const int*   gid  = (const int*)d_in[4];
    const float* W1   = (const float*)d_in[5];
    const float* b1   = (const float*)d_in[6];
    const float* g1   = (const float*)d_in[7];
    const float* be1  = (const float*)d_in[8];
    const float* W2   = (const float*)d_in[9];
    const float* b2   = (const float*)d_in[10];
    const float* eps  = (const float*)d_in[11];
    const float* ng   = (const float*)d_in[12];
    const float* nb   = (const float*)d_in[13];
    const float* fc1W = (const float*)d_in[14];
    const float* fc1b = (const float*)d_in[15];
    const float* n1g  = (const float*)d_in[16];
    const float* n1b  = (const float*)d_in[17];
    const float* fc2W = (const float*)d_in[18];
    const float* fc2b = (const float*)d_in[19];
    float* out = (float*)d_out;

    float* nx = (float*)d_ws;                         // NN*DD f32
    _Float16* x16 = (_Float16*)(nx + (size_t)NN * DD);
    _Float16* h16 = x16 + (size_t)NN * DD;
    float* hg = (float*)(h16 + (size_t)NN * DD);      // NG*DD
    int* row_ptr = (int*)(hg + (size_t)NG * DD);
    int* col     = row_ptr + NN + 4;
    int* btot    = col + NE;
    int* hist    = btot + 512;                        // NBK*256
    _Float16* wt = (_Float16*)(((uintptr_t)(hist + NBK * 256) + 255) & ~(uintptr_t)255);
    unsigned* pairs = (unsigned*)x16;                 // overlay: dead before layer-0 agg

    wprep_k<<<(6 * 16384 + 255) / 256, 256, 0, stream>>>(W1, W2, wt);
    h16init_k<<<(NN * DD / 4 + 255) / 256, 256, 0, stream>>>(h, h16);

    hist_k<<<256, 256, 0, stream>>>(dst, hist);
    bucketpref_k<<<NBK, 256, 0, stream>>>(hist, btot);
    scan_bsums2_k<<<1, 512, 0, stream>>>(btot, NBK, row_ptr);
    scatter_pairs_k<<<256, 256, 0, stream>>>(src, dst, btot, hist, pairs);
    bucket_csr_k<<<NBK, 256, 0, stream>>>(pairs, btot, row_ptr, col);

    const int mlp_grid = (NN + 63) / 64;   // 1563
    const float* cur = h;
    for (int l = 0; l < NL; ++l) {
        const _Float16* w1hi = wt + (size_t)(l * 2 + 0) * 2 * 16384;
        const _Float16* w1lo = w1hi + 16384;
        const _Float16* w2hi = wt + (size_t)(l * 2 + 1) * 2 * 16384;
        const _Float16* w2lo = w2hi + 16384;
        agg_k<<<(NN + 7) / 8, 256, 0, stream>>>(cur, h16, row_ptr, col, x16, eps, l);
        mlp_k<<<mlp_grid, 256, 0, stream>>>(
            x16, w1hi, w1lo, w2hi, w2lo,
            b1 + l * DD, g1 + l * DD, be1 + l * DD,
            b2 + l * DD, ng + l * DD, nb + l * DD,
            nx, (l < NL - 1) ? h16 : nullptr, NN);
        cur = nx;
    }
    zero_int_k<<<(NG * DD + 255) / 256, 256, 0, stream>>>((int*)hg, NG * DD);
    pool_k<<<(NN + 127) / 128, 256, 0, stream>>>(cur, gid, hg);
    head2_k<<<NG, 128, 0, stream>>>(hg, desc, fc1W, fc1b, n1g, n1b, fc2W, fc2b, out);
}